// Round 1
// baseline (2472.513 us; speedup 1.0000x reference)
//
#include <hip/hip_runtime.h>

#define TID ((int)threadIdx.x)

// ---------------- workspace layout (float offsets) ----------------
static constexpr long QW1_OFF  = 16;        // 800
static constexpr long QW2_OFF  = 1024;      // 51200
static constexpr long QWF1_OFF = 52224;     // 524288
static constexpr long QWF2_OFF = 576512;    // 5120
static constexpr long TMAX_OFF = 581632;    // 4 (uint bits of abs-max)
static constexpr long SUM1_OFF = 581664, SSQ1_OFF = 581696, SC1_OFF = 581728, SH1_OFF = 581760;
static constexpr long SUM2_OFF = 581792, SSQ2_OFF = 581856, SC2_OFF = 581920, SH2_OFF = 581984;
static constexpr long SUM3_OFF = 582048, SSQ3_OFF = 582560, SC3_OFF = 583072, SH3_OFF = 583584;
static constexpr long STATS_BEG = TMAX_OFF, STATS_END = 584096;
static constexpr long H1_OFF = 584192;                    // [N=4096][C=32][12][12]
static constexpr long Y2_OFF = H1_OFF + 18874368L;        // [OC=64][N=4096][8][8]
static constexpr long H2_OFF = Y2_OFF + 16777216L;        // [N=4096][1024]
static constexpr long Y3_OFF = H2_OFF + 4194304L;         // [J=512][N=4096] (transposed)
// total = 42,527,232 floats = 170.1 MB of d_ws

// ---------------- abs-max of the 4 weight tensors ----------------
__global__ __launch_bounds__(256) void absmax_k(const float* w1, const float* w2,
                                                const float* wf1, const float* wf2,
                                                unsigned int* tmaxbits) {
    int bid = blockIdx.x;
    int b, lb, nb; const float* src; long n;
    if (bid < 1)       { b = 0; src = w1;  n = 800;    lb = bid;      nb = 1;  }
    else if (bid < 9)  { b = 1; src = w2;  n = 51200;  lb = bid - 1;  nb = 8;  }
    else if (bid < 73) { b = 2; src = wf1; n = 524288; lb = bid - 9;  nb = 64; }
    else               { b = 3; src = wf2; n = 5120;   lb = bid - 73; nb = 1;  }
    float m = 0.f;
    for (long i = (long)lb * 256 + TID; i < n; i += (long)nb * 256)
        m = fmaxf(m, fabsf(src[i]));
    __shared__ float red[256];
    red[TID] = m; __syncthreads();
    for (int s = 128; s > 0; s >>= 1) {
        if (TID < s) red[TID] = fmaxf(red[TID], red[TID + s]);
        __syncthreads();
    }
    // non-negative floats order like their uint bit patterns
    if (TID == 0) atomicMax(&tmaxbits[b], __float_as_uint(red[0]));
}

// ---------------- ternary quantization ----------------
__global__ __launch_bounds__(256) void quant_k(const float* w, float* q, int n,
                                               const unsigned int* tmaxbits, int b) {
    int i = blockIdx.x * 256 + TID;
    if (i >= n) return;
    float t = 0.05f * __uint_as_float(tmaxbits[b]);
    float v = w[i];
    q[i] = (v > t) ? 1.f : ((v < -t) ? -1.f : 0.f);
}

// ---------------- conv1 pass A: stats only (no store) ----------------
// x: [4096][1][28][28]; qw1: [32][25]; 24x24 valid outputs.
__global__ __launch_bounds__(256) void conv1_stats_k(const float* __restrict__ x,
                                                     const float* __restrict__ qw1,
                                                     float* sum, float* ssq) {
    int c = blockIdx.y;
    __shared__ float wl[25];
    __shared__ float r1[256], r2[256];
    if (TID < 25) wl[TID] = qw1[c * 25 + TID];
    __syncthreads();
    float s = 0.f, s2 = 0.f;
    #pragma unroll
    for (int j = 0; j < 4; j++) {
        int p = blockIdx.x * 1024 + j * 256 + TID;   // < 4096*576 exactly
        int n = p / 576, hw = p % 576;
        int oy = hw / 24, ox = hw % 24;
        const float* xb = x + n * 784 + oy * 28 + ox;
        float acc = 0.f;
        #pragma unroll
        for (int ky = 0; ky < 5; ky++)
            #pragma unroll
            for (int kx = 0; kx < 5; kx++)
                acc += xb[ky * 28 + kx] * wl[ky * 5 + kx];
        s += acc; s2 += acc * acc;
    }
    r1[TID] = s; r2[TID] = s2; __syncthreads();
    for (int st = 128; st > 0; st >>= 1) {
        if (TID < st) { r1[TID] += r1[TID + st]; r2[TID] += r2[TID + st]; }
        __syncthreads();
    }
    if (TID == 0) { atomicAdd(&sum[c], r1[0]); atomicAdd(&ssq[c], r2[0]); }
}

// ---------------- BN finalize: scale/shift from sums ----------------
__global__ void bn_fin_k(const float* sum, const float* ssq, const float* g,
                         const float* be, float* sc, float* sh, float inv_cnt, int C) {
    int c = blockIdx.x * 256 + TID;
    if (c >= C) return;
    float m = sum[c] * inv_cnt;
    float v = ssq[c] * inv_cnt - m * m;
    float s = g[c] / sqrtf(v + 1e-5f);
    sc[c] = s; sh[c] = be[c] - m * s;
}

// ---------------- conv1 pass B: conv + BN + relu + maxpool fused ----------------
// writes h1: [N][32][12][12]
__global__ __launch_bounds__(256) void conv1_pool_k(const float* __restrict__ x,
                                                    const float* __restrict__ qw1,
                                                    const float* sc, const float* sh,
                                                    float* __restrict__ h1) {
    int c = blockIdx.y;
    __shared__ float wl[25];
    if (TID < 25) wl[TID] = qw1[c * 25 + TID];
    __syncthreads();
    int p = blockIdx.x * 256 + TID;          // < 4096*144 exactly
    int n = p / 144, hw = p % 144;
    int py = hw / 12, px = hw % 12;
    float scl = sc[c], shf = sh[c];
    float m = 0.f;                            // relu floor; safe init
    #pragma unroll
    for (int dy = 0; dy < 2; dy++)
        #pragma unroll
        for (int dx = 0; dx < 2; dx++) {
            int oy = 2 * py + dy, ox = 2 * px + dx;
            const float* xb = x + n * 784 + oy * 28 + ox;
            float acc = 0.f;
            #pragma unroll
            for (int ky = 0; ky < 5; ky++)
                #pragma unroll
                for (int kx = 0; kx < 5; kx++)
                    acc += xb[ky * 28 + kx] * wl[ky * 5 + kx];
            m = fmaxf(m, fmaxf(acc * scl + shf, 0.f));
        }
    h1[(n * 32 + c) * 144 + hw] = m;
}

// ---------------- conv2: thread computes one 8-wide output row; fused stats ----------------
// h1: [N][32][12][12]; qw2: [64][800]; y2: [OC][N][8][8]
__global__ __launch_bounds__(256) void conv2_k(const float* __restrict__ h1,
                                               const float* __restrict__ qw2,
                                               float* __restrict__ y2,
                                               float* sum, float* ssq) {
    int oc = blockIdx.y;
    __shared__ float wl[800];
    __shared__ float r1[256], r2[256];
    for (int i = TID; i < 800; i += 256) wl[i] = qw2[oc * 800 + i];
    __syncthreads();
    int p = blockIdx.x * 256 + TID;          // < 4096*8 exactly
    int n = p >> 3, oy = p & 7;
    float acc[8] = {0, 0, 0, 0, 0, 0, 0, 0};
    for (int ic = 0; ic < 32; ic++) {
        const float* hb = h1 + (n * 32 + ic) * 144;
        const float* wr = &wl[ic * 25];
        #pragma unroll
        for (int ky = 0; ky < 5; ky++) {
            const float4* rp = reinterpret_cast<const float4*>(hb + (oy + ky) * 12);
            float4 a0 = rp[0], a1 = rp[1], a2 = rp[2];
            float r[12] = {a0.x, a0.y, a0.z, a0.w, a1.x, a1.y, a1.z, a1.w,
                           a2.x, a2.y, a2.z, a2.w};
            #pragma unroll
            for (int kx = 0; kx < 5; kx++) {
                float w = wr[ky * 5 + kx];
                #pragma unroll
                for (int ox = 0; ox < 8; ox++) acc[ox] += r[ox + kx] * w;
            }
        }
    }
    float s = 0.f, s2 = 0.f;
    int base = (oc * 4096 + n) * 64 + oy * 8;
    #pragma unroll
    for (int ox = 0; ox < 8; ox++) {
        y2[base + ox] = acc[ox];
        s += acc[ox]; s2 += acc[ox] * acc[ox];
    }
    r1[TID] = s; r2[TID] = s2; __syncthreads();
    for (int st = 128; st > 0; st >>= 1) {
        if (TID < st) { r1[TID] += r1[TID + st]; r2[TID] += r2[TID + st]; }
        __syncthreads();
    }
    if (TID == 0) { atomicAdd(&sum[oc], r1[0]); atomicAdd(&ssq[oc], r2[0]); }
}

// ---------------- pool2: BN + relu + maxpool; writes flattened h2 [N][1024] ----------------
__global__ __launch_bounds__(256) void pool2_k(const float* __restrict__ y2,
                                               const float* sc, const float* sh,
                                               float* __restrict__ h2) {
    int i = blockIdx.x * 256 + TID;          // < 4096*64*16 exactly
    int hw = i & 15, oc = (i >> 4) & 63, n = i >> 10;
    int py = hw >> 2, px = hw & 3;
    int base = (oc * 4096 + n) * 64 + (2 * py) * 8 + 2 * px;
    float s = sc[oc], t = sh[oc];
    float a = y2[base] * s + t, b = y2[base + 1] * s + t;
    float c = y2[base + 8] * s + t, d = y2[base + 9] * s + t;
    float m = fmaxf(fmaxf(fmaxf(fmaxf(0.f, a), b), c), d);  // relu then max
    h2[i] = m;                                // i == n*1024 + oc*16 + py*4 + px
}

// ---------------- fc1: [4096x1024] @ [512x1024]^T -> y3T [512][4096] ----------------
__global__ __launch_bounds__(256) void fc1_k(const float* __restrict__ h2,
                                             const float* __restrict__ qwf1,
                                             float* __restrict__ y3T) {
    __shared__ float As[16][66], Bs[16][66];  // +2 pad: conflict-free strided access
    int tx = TID & 15, ty = TID >> 4;
    int n0 = blockIdx.x * 64, j0 = blockIdx.y * 64;
    float acc[4][4] = {};
    int e = TID * 4, ia = e >> 4, ka = e & 15;
    for (int kk = 0; kk < 1024; kk += 16) {
        float4 av = *reinterpret_cast<const float4*>(h2 + (n0 + ia) * 1024 + kk + ka);
        As[ka + 0][ia] = av.x; As[ka + 1][ia] = av.y; As[ka + 2][ia] = av.z; As[ka + 3][ia] = av.w;
        float4 bv = *reinterpret_cast<const float4*>(qwf1 + (j0 + ia) * 1024 + kk + ka);
        Bs[ka + 0][ia] = bv.x; Bs[ka + 1][ia] = bv.y; Bs[ka + 2][ia] = bv.z; Bs[ka + 3][ia] = bv.w;
        __syncthreads();
        #pragma unroll
        for (int k = 0; k < 16; k++) {
            float a[4], b[4];
            #pragma unroll
            for (int l = 0; l < 4; l++) a[l] = As[k][tx + 16 * l];
            #pragma unroll
            for (int mth = 0; mth < 4; mth++) b[mth] = Bs[k][ty + 16 * mth];
            #pragma unroll
            for (int l = 0; l < 4; l++)
                #pragma unroll
                for (int mth = 0; mth < 4; mth++) acc[l][mth] += a[l] * b[mth];
        }
        __syncthreads();
    }
    #pragma unroll
    for (int mth = 0; mth < 4; mth++)
        #pragma unroll
        for (int l = 0; l < 4; l++)
            y3T[(j0 + ty + 16 * mth) * 4096 + n0 + tx + 16 * l] = acc[l][mth];
}

// ---------------- bn3 stats: per-feature sums over N (coalesced on y3T) ----------------
__global__ __launch_bounds__(256) void bn3_stats_k(const float* __restrict__ y3T,
                                                   float* sum, float* ssq) {
    int j = blockIdx.x;
    __shared__ float r1[256], r2[256];
    float s = 0.f, s2 = 0.f;
    for (int n = TID; n < 4096; n += 256) {
        float v = y3T[j * 4096 + n];
        s += v; s2 += v * v;
    }
    r1[TID] = s; r2[TID] = s2; __syncthreads();
    for (int st = 128; st > 0; st >>= 1) {
        if (TID < st) { r1[TID] += r1[TID + st]; r2[TID] += r2[TID + st]; }
        __syncthreads();
    }
    if (TID == 0) { sum[j] = r1[0]; ssq[j] = r2[0]; }
}

// ---------------- fc2: BN3+relu applied on the fly; out [4096][10] ----------------
__global__ __launch_bounds__(256) void fc2_k(const float* __restrict__ y3T,
                                             const float* sc, const float* sh,
                                             const float* __restrict__ qwf2,
                                             const float* bf2, float* __restrict__ out) {
    __shared__ float wl[5120];
    for (int i = TID; i < 5120; i += 256) wl[i] = qwf2[i];
    __syncthreads();
    int n = blockIdx.x * 256 + TID;
    float acc[10] = {};
    for (int k = 0; k < 512; k++) {
        float v = fmaxf(y3T[k * 4096 + n] * sc[k] + sh[k], 0.f);
        #pragma unroll
        for (int o = 0; o < 10; o++) acc[o] += v * wl[o * 512 + k];
    }
    #pragma unroll
    for (int o = 0; o < 10; o++) out[n * 10 + o] = acc[o] + bf2[o];
}

extern "C" void kernel_launch(void* const* d_in, const int* in_sizes, int n_in,
                              void* d_out, int out_size, void* d_ws, size_t ws_size,
                              hipStream_t stream) {
    float* ws = (float*)d_ws;
    const float* x   = (const float*)d_in[0];
    const float* w1  = (const float*)d_in[1];
    // b1 = d_in[2]  : cancels under training-mode BN
    const float* g1  = (const float*)d_in[3];
    const float* be1 = (const float*)d_in[4];
    const float* w2  = (const float*)d_in[5];
    // b2 = d_in[6]  : cancels
    const float* g2  = (const float*)d_in[7];
    const float* be2 = (const float*)d_in[8];
    const float* wf1 = (const float*)d_in[9];
    // bf1 = d_in[10]: cancels
    const float* g3  = (const float*)d_in[11];
    const float* be3 = (const float*)d_in[12];
    const float* wf2 = (const float*)d_in[13];
    const float* bf2 = (const float*)d_in[14];
    float* out = (float*)d_out;

    unsigned int* tmax = (unsigned int*)(ws + TMAX_OFF);
    float* qw1  = ws + QW1_OFF;
    float* qw2  = ws + QW2_OFF;
    float* qwf1 = ws + QWF1_OFF;
    float* qwf2 = ws + QWF2_OFF;
    float* h1 = ws + H1_OFF;
    float* y2 = ws + Y2_OFF;
    float* h2 = ws + H2_OFF;
    float* y3 = ws + Y3_OFF;

    // zero stats + tmax region (d_ws is poisoned 0xAA before every launch)
    hipMemsetAsync(ws + STATS_BEG, 0, (STATS_END - STATS_BEG) * sizeof(float), stream);

    absmax_k<<<74, 256, 0, stream>>>(w1, w2, wf1, wf2, tmax);
    quant_k<<<4, 256, 0, stream>>>(w1, qw1, 800, tmax, 0);
    quant_k<<<200, 256, 0, stream>>>(w2, qw2, 51200, tmax, 1);
    quant_k<<<2048, 256, 0, stream>>>(wf1, qwf1, 524288, tmax, 2);
    quant_k<<<20, 256, 0, stream>>>(wf2, qwf2, 5120, tmax, 3);

    conv1_stats_k<<<dim3(2304, 32), 256, 0, stream>>>(x, qw1, ws + SUM1_OFF, ws + SSQ1_OFF);
    bn_fin_k<<<1, 256, 0, stream>>>(ws + SUM1_OFF, ws + SSQ1_OFF, g1, be1,
                                    ws + SC1_OFF, ws + SH1_OFF, 1.f / 2359296.f, 32);
    conv1_pool_k<<<dim3(2304, 32), 256, 0, stream>>>(x, qw1, ws + SC1_OFF, ws + SH1_OFF, h1);

    conv2_k<<<dim3(128, 64), 256, 0, stream>>>(h1, qw2, y2, ws + SUM2_OFF, ws + SSQ2_OFF);
    bn_fin_k<<<1, 256, 0, stream>>>(ws + SUM2_OFF, ws + SSQ2_OFF, g2, be2,
                                    ws + SC2_OFF, ws + SH2_OFF, 1.f / 262144.f, 64);
    pool2_k<<<16384, 256, 0, stream>>>(y2, ws + SC2_OFF, ws + SH2_OFF, h2);

    fc1_k<<<dim3(64, 8), 256, 0, stream>>>(h2, qwf1, y3);
    bn3_stats_k<<<512, 256, 0, stream>>>(y3, ws + SUM3_OFF, ws + SSQ3_OFF);
    bn_fin_k<<<2, 256, 0, stream>>>(ws + SUM3_OFF, ws + SSQ3_OFF, g3, be3,
                                    ws + SC3_OFF, ws + SH3_OFF, 1.f / 4096.f, 512);

    fc2_k<<<16, 256, 0, stream>>>(y3, ws + SC3_OFF, ws + SH3_OFF, qwf2, bf2, out);
}

// Round 4
// 909.978 us; speedup vs baseline: 2.7171x; 2.7171x over previous
//
#include <hip/hip_runtime.h>

#define TID ((int)threadIdx.x)

// ---------------- workspace layout (float offsets) ----------------
static constexpr long QW1_OFF  = 16;        // 800
static constexpr long QW2_OFF  = 1024;      // 51200
static constexpr long QWF1_OFF = 52224;     // 524288
static constexpr long QWF2_OFF = 576512;    // 5120
static constexpr long TMAX_OFF = 581632;    // 4 (uint bits of abs-max)
static constexpr long SUM1_OFF = 581664, SSQ1_OFF = 581696, SC1_OFF = 581728, SH1_OFF = 581760;
static constexpr long SUM2_OFF = 581792, SSQ2_OFF = 581856, SC2_OFF = 581920, SH2_OFF = 581984;
static constexpr long SUM3_OFF = 582048, SSQ3_OFF = 582560, SC3_OFF = 583072, SH3_OFF = 583584;
static constexpr long STATS_BEG = TMAX_OFF, STATS_END = 584096;
static constexpr long H1_OFF = 584192;                    // [N=4096][C=32][12][12]
static constexpr long Y2_OFF = H1_OFF + 18874368L;        // [N=4096][OC=64][8][8]
static constexpr long H2_OFF = Y2_OFF + 16777216L;        // [N=4096][1024]
static constexpr long Y3_OFF = H2_OFF + 4194304L;         // [J=512][N=4096] (transposed)
// total = 42,527,232 floats = 170.1 MB of d_ws

// ---------------- abs-max of the 4 weight tensors ----------------
__global__ __launch_bounds__(256) void absmax_k(const float* w1, const float* w2,
                                                const float* wf1, const float* wf2,
                                                unsigned int* tmaxbits) {
    int bid = blockIdx.x;
    int b, lb, nb; const float* src; long n;
    if (bid < 1)       { b = 0; src = w1;  n = 800;    lb = bid;      nb = 1;  }
    else if (bid < 9)  { b = 1; src = w2;  n = 51200;  lb = bid - 1;  nb = 8;  }
    else if (bid < 73) { b = 2; src = wf1; n = 524288; lb = bid - 9;  nb = 64; }
    else               { b = 3; src = wf2; n = 5120;   lb = bid - 73; nb = 1;  }
    float m = 0.f;
    for (long i = (long)lb * 256 + TID; i < n; i += (long)nb * 256)
        m = fmaxf(m, fabsf(src[i]));
    __shared__ float red[256];
    red[TID] = m; __syncthreads();
    for (int s = 128; s > 0; s >>= 1) {
        if (TID < s) red[TID] = fmaxf(red[TID], red[TID + s]);
        __syncthreads();
    }
    if (TID == 0) atomicMax(&tmaxbits[b], __float_as_uint(red[0]));
}

// ---------------- ternary quantization ----------------
__global__ __launch_bounds__(256) void quant_k(const float* w, float* q, int n,
                                               const unsigned int* tmaxbits, int b) {
    int i = blockIdx.x * 256 + TID;
    if (i >= n) return;
    float t = 0.05f * __uint_as_float(tmaxbits[b]);
    float v = w[i];
    q[i] = (v > t) ? 1.f : ((v < -t) ? -1.f : 0.f);
}

// ---------------- conv1 pass A: stats only. thread = (n, oy), 24 outputs ----------------
__global__ __launch_bounds__(256) void conv1_stats_k(const float* __restrict__ x,
                                                     const float* __restrict__ qw1,
                                                     float* sum, float* ssq) {
    int c = blockIdx.y;
    __shared__ float wl[25];
    __shared__ float r1[256], r2[256];
    if (TID < 25) wl[TID] = qw1[c * 25 + TID];
    __syncthreads();
    int p = blockIdx.x * 256 + TID;          // < 4096*24 exactly (grid.x = 384)
    int n = p / 24, oy = p % 24;
    const float* xb = x + n * 784 + oy * 28;
    float acc[24] = {};
    #pragma unroll
    for (int r = 0; r < 5; r++) {
        float rr[28];
        const float4* rp = reinterpret_cast<const float4*>(xb + r * 28);
        #pragma unroll
        for (int q = 0; q < 7; q++) {
            float4 v = rp[q];
            rr[q * 4 + 0] = v.x; rr[q * 4 + 1] = v.y; rr[q * 4 + 2] = v.z; rr[q * 4 + 3] = v.w;
        }
        #pragma unroll
        for (int kx = 0; kx < 5; kx++) {
            float wv = wl[r * 5 + kx];
            #pragma unroll
            for (int ox = 0; ox < 24; ox++) acc[ox] = fmaf(rr[ox + kx], wv, acc[ox]);
        }
    }
    float s = 0.f, s2 = 0.f;
    #pragma unroll
    for (int ox = 0; ox < 24; ox++) { s += acc[ox]; s2 += acc[ox] * acc[ox]; }
    r1[TID] = s; r2[TID] = s2; __syncthreads();
    for (int st = 128; st > 0; st >>= 1) {
        if (TID < st) { r1[TID] += r1[TID + st]; r2[TID] += r2[TID + st]; }
        __syncthreads();
    }
    if (TID == 0) { atomicAdd(&sum[c], r1[0]); atomicAdd(&ssq[c], r2[0]); }
}

// ---------------- BN finalize ----------------
__global__ void bn_fin_k(const float* sum, const float* ssq, const float* g,
                         const float* be, float* sc, float* sh, float inv_cnt, int C) {
    int c = blockIdx.x * 256 + TID;
    if (c >= C) return;
    float m = sum[c] * inv_cnt;
    float v = ssq[c] * inv_cnt - m * m;
    float s = g[c] / sqrtf(v + 1e-5f);
    sc[c] = s; sh[c] = be[c] - m * s;
}

// ---------------- conv1 pass B: thread = (n, py) py in 0..11; 2 conv rows -> 1 pooled row ----------------
__global__ __launch_bounds__(256) void conv1_pool_k(const float* __restrict__ x,
                                                    const float* __restrict__ qw1,
                                                    const float* sc, const float* sh,
                                                    float* __restrict__ h1) {
    int c = blockIdx.y;
    __shared__ float wl[25];
    if (TID < 25) wl[TID] = qw1[c * 25 + TID];
    __syncthreads();
    int p = blockIdx.x * 256 + TID;          // < 4096*12 exactly (grid.x = 192)
    int n = p / 12, py = p % 12;
    const float* xb = x + n * 784 + (2 * py) * 28;
    float acc[2][24] = {};
    #pragma unroll
    for (int lr = 0; lr < 6; lr++) {
        float rr[28];
        const float4* rp = reinterpret_cast<const float4*>(xb + lr * 28);
        #pragma unroll
        for (int q = 0; q < 7; q++) {
            float4 v = rp[q];
            rr[q * 4 + 0] = v.x; rr[q * 4 + 1] = v.y; rr[q * 4 + 2] = v.z; rr[q * 4 + 3] = v.w;
        }
        #pragma unroll
        for (int cl = 0; cl < 2; cl++) {
            int ky = lr - cl;
            if (ky < 0 || ky > 4) continue;
            #pragma unroll
            for (int kx = 0; kx < 5; kx++) {
                float wv = wl[ky * 5 + kx];
                #pragma unroll
                for (int ox = 0; ox < 24; ox++) acc[cl][ox] = fmaf(rr[ox + kx], wv, acc[cl][ox]);
            }
        }
    }
    float scl = sc[c], shf = sh[c];
    float hrow[12];
    #pragma unroll
    for (int px = 0; px < 12; px++) {
        float a = fmaxf(acc[0][2 * px] * scl + shf, 0.f);
        float b = fmaxf(acc[0][2 * px + 1] * scl + shf, 0.f);
        float d = fmaxf(acc[1][2 * px] * scl + shf, 0.f);
        float e = fmaxf(acc[1][2 * px + 1] * scl + shf, 0.f);
        hrow[px] = fmaxf(fmaxf(a, b), fmaxf(d, e));
    }
    float* hp = h1 + ((long)n * 32 + c) * 144 + py * 12;
    #pragma unroll
    for (int q = 0; q < 3; q++)
        *reinterpret_cast<float4*>(hp + q * 4) =
            make_float4(hrow[q * 4], hrow[q * 4 + 1], hrow[q * 4 + 2], hrow[q * 4 + 3]);
}

// ---------------- conv2: LDS-blocked. block = 8 n x 32 oc; thread = (n,oc), 8x8 out ----------------
// h1: [N][32][144]; qw2: [64][800]; y2: [N][64][8][8]
__global__ __launch_bounds__(256, 2) void conv2_k(const float* __restrict__ h1,
                                                  const float* __restrict__ qw2,
                                                  float* __restrict__ y2,
                                                  float* sum, float* ssq) {
    __shared__ float hs[9216];     // [8 n][8 ic][144]
    __shared__ float wl[6432];     // [32 oc][201]  (8 ic * 25, +1 pad)
    __shared__ float r1[256], r2[256];
    int n0 = blockIdx.x * 8;       // grid.x = 512
    int oc0 = blockIdx.y * 32;     // grid.y = 2
    int nl = TID >> 5, ocl = TID & 31;
    float acc[64] = {};
    for (int ch = 0; ch < 4; ch++) {
        int ic0 = ch * 8;
        __syncthreads();
        #pragma unroll
        for (int k = 0; k < 9; k++) {
            int q = TID + k * 256;                 // < 2304
            int n = q / 288, rem = q % 288;
            int ic = rem / 36, pos = rem - ic * 36;
            float4 v = *reinterpret_cast<const float4*>(
                h1 + ((long)(n0 + n) * 32 + ic0 + ic) * 144 + pos * 4);
            *reinterpret_cast<float4*>(hs + (n * 8 + ic) * 144 + pos * 4) = v;
        }
        #pragma unroll
        for (int k = 0; k < 25; k++) {
            int q = TID + k * 256;                 // < 6400
            int oc = q / 200, j = q - oc * 200;
            wl[oc * 201 + j] = qw2[(long)(oc0 + oc) * 800 + ic0 * 25 + j];
        }
        __syncthreads();
        #pragma unroll 1
        for (int ic = 0; ic < 8; ic++) {
            const float* hp = hs + (nl * 8 + ic) * 144;
            float w[25];
            #pragma unroll
            for (int j = 0; j < 25; j++) w[j] = wl[ocl * 201 + ic * 25 + j];
            #pragma unroll
            for (int r = 0; r < 12; r++) {
                float rr[12];
                float4 a0 = *reinterpret_cast<const float4*>(hp + r * 12);
                float4 a1 = *reinterpret_cast<const float4*>(hp + r * 12 + 4);
                float4 a2 = *reinterpret_cast<const float4*>(hp + r * 12 + 8);
                rr[0] = a0.x; rr[1] = a0.y; rr[2]  = a0.z; rr[3]  = a0.w;
                rr[4] = a1.x; rr[5] = a1.y; rr[6]  = a1.z; rr[7]  = a1.w;
                rr[8] = a2.x; rr[9] = a2.y; rr[10] = a2.z; rr[11] = a2.w;
                #pragma unroll
                for (int ky = 0; ky < 5; ky++) {
                    int oy = r - ky;
                    if (oy < 0 || oy > 7) continue;
                    #pragma unroll
                    for (int kx = 0; kx < 5; kx++) {
                        float wv = w[ky * 5 + kx];
                        #pragma unroll
                        for (int ox = 0; ox < 8; ox++)
                            acc[oy * 8 + ox] = fmaf(rr[ox + kx], wv, acc[oy * 8 + ox]);
                    }
                }
            }
        }
    }
    // write y2 [n][oc][64]
    float4* yp = reinterpret_cast<float4*>(y2 + ((long)(n0 + nl) * 64 + oc0 + ocl) * 64);
    float s = 0.f, s2 = 0.f;
    #pragma unroll
    for (int i = 0; i < 16; i++) {
        yp[i] = make_float4(acc[4 * i], acc[4 * i + 1], acc[4 * i + 2], acc[4 * i + 3]);
        #pragma unroll
        for (int j = 0; j < 4; j++) { float v = acc[4 * i + j]; s += v; s2 += v * v; }
    }
    r1[TID] = s; r2[TID] = s2; __syncthreads();
    if (TID < 32) {
        float ts = 0.f, t2 = 0.f;
        #pragma unroll
        for (int j = 0; j < 8; j++) { ts += r1[TID + 32 * j]; t2 += r2[TID + 32 * j]; }
        atomicAdd(&sum[oc0 + TID], ts); atomicAdd(&ssq[oc0 + TID], t2);
    }
}

// ---------------- pool2: BN + relu + maxpool; h2 [N][1024] ----------------
__global__ __launch_bounds__(256) void pool2_k(const float* __restrict__ y2,
                                               const float* sc, const float* sh,
                                               float* __restrict__ h2) {
    int i = blockIdx.x * 256 + TID;          // < 4096*64*16 exactly
    int hw = i & 15, oc = (i >> 4) & 63, n = i >> 10;
    int py = hw >> 2, px = hw & 3;
    long base = ((long)n * 64 + oc) * 64 + (2 * py) * 8 + 2 * px;
    float s = sc[oc], t = sh[oc];
    float a = y2[base] * s + t, b = y2[base + 1] * s + t;
    float c = y2[base + 8] * s + t, d = y2[base + 9] * s + t;
    float m = fmaxf(fmaxf(fmaxf(fmaxf(0.f, a), b), c), d);
    h2[i] = m;                                // i == n*1024 + oc*16 + py*4 + px
}

// ---------------- fc1: [4096x1024] @ [512x1024]^T -> y3T [512][4096] ----------------
__global__ __launch_bounds__(256) void fc1_k(const float* __restrict__ h2,
                                             const float* __restrict__ qwf1,
                                             float* __restrict__ y3T) {
    __shared__ float As[16][66], Bs[16][66];
    int tx = TID & 15, ty = TID >> 4;
    int n0 = blockIdx.x * 64, j0 = blockIdx.y * 64;
    float acc[4][4] = {};
    int e = TID * 4, ia = e >> 4, ka = e & 15;
    for (int kk = 0; kk < 1024; kk += 16) {
        float4 av = *reinterpret_cast<const float4*>(h2 + (n0 + ia) * 1024 + kk + ka);
        As[ka + 0][ia] = av.x; As[ka + 1][ia] = av.y; As[ka + 2][ia] = av.z; As[ka + 3][ia] = av.w;
        float4 bv = *reinterpret_cast<const float4*>(qwf1 + (j0 + ia) * 1024 + kk + ka);
        Bs[ka + 0][ia] = bv.x; Bs[ka + 1][ia] = bv.y; Bs[ka + 2][ia] = bv.z; Bs[ka + 3][ia] = bv.w;
        __syncthreads();
        #pragma unroll
        for (int k = 0; k < 16; k++) {
            float a[4], b[4];
            #pragma unroll
            for (int l = 0; l < 4; l++) a[l] = As[k][tx + 16 * l];
            #pragma unroll
            for (int mth = 0; mth < 4; mth++) b[mth] = Bs[k][ty + 16 * mth];
            #pragma unroll
            for (int l = 0; l < 4; l++)
                #pragma unroll
                for (int mth = 0; mth < 4; mth++) acc[l][mth] += a[l] * b[mth];
        }
        __syncthreads();
    }
    #pragma unroll
    for (int mth = 0; mth < 4; mth++)
        #pragma unroll
        for (int l = 0; l < 4; l++)
            y3T[(j0 + ty + 16 * mth) * 4096 + n0 + tx + 16 * l] = acc[l][mth];
}

// ---------------- bn3 stats ----------------
__global__ __launch_bounds__(256) void bn3_stats_k(const float* __restrict__ y3T,
                                                   float* sum, float* ssq) {
    int j = blockIdx.x;
    __shared__ float r1[256], r2[256];
    float s = 0.f, s2 = 0.f;
    for (int n = TID; n < 4096; n += 256) {
        float v = y3T[j * 4096 + n];
        s += v; s2 += v * v;
    }
    r1[TID] = s; r2[TID] = s2; __syncthreads();
    for (int st = 128; st > 0; st >>= 1) {
        if (TID < st) { r1[TID] += r1[TID + st]; r2[TID] += r2[TID + st]; }
        __syncthreads();
    }
    if (TID == 0) { sum[j] = r1[0]; ssq[j] = r2[0]; }
}

// ---------------- fc2: K-sliced; block = 64 n x 4 k-slices; grid.x = 64 ----------------
__global__ __launch_bounds__(256) void fc2_k(const float* __restrict__ y3T,
                                             const float* sc, const float* sh,
                                             const float* __restrict__ qwf2,
                                             const float* bf2, float* __restrict__ out) {
    __shared__ float wlds[5120];
    __shared__ float part[3][640];
    for (int i = TID; i < 5120; i += 256) wlds[i] = qwf2[i];
    __syncthreads();
    int nl = TID & 63, ks = TID >> 6;
    int n = blockIdx.x * 64 + nl;            // grid.x = 64
    float acc[10] = {};
    for (int k = ks * 128; k < ks * 128 + 128; k++) {
        float v = fmaxf(y3T[k * 4096 + n] * sc[k] + sh[k], 0.f);
        #pragma unroll
        for (int o = 0; o < 10; o++) acc[o] = fmaf(v, wlds[o * 512 + k], acc[o]);
    }
    if (ks > 0) {
        #pragma unroll
        for (int o = 0; o < 10; o++) part[ks - 1][o * 64 + nl] = acc[o];
    }
    __syncthreads();
    if (ks == 0) {
        #pragma unroll
        for (int o = 0; o < 10; o++)
            out[n * 10 + o] = acc[o] + part[0][o * 64 + nl] + part[1][o * 64 + nl]
                              + part[2][o * 64 + nl] + bf2[o];
    }
}

extern "C" void kernel_launch(void* const* d_in, const int* in_sizes, int n_in,
                              void* d_out, int out_size, void* d_ws, size_t ws_size,
                              hipStream_t stream) {
    float* ws = (float*)d_ws;
    const float* x   = (const float*)d_in[0];
    const float* w1  = (const float*)d_in[1];
    // b1/b2/bf1 cancel under training-mode BN
    const float* g1  = (const float*)d_in[3];
    const float* be1 = (const float*)d_in[4];
    const float* w2  = (const float*)d_in[5];
    const float* g2  = (const float*)d_in[7];
    const float* be2 = (const float*)d_in[8];
    const float* wf1 = (const float*)d_in[9];
    const float* g3  = (const float*)d_in[11];
    const float* be3 = (const float*)d_in[12];
    const float* wf2 = (const float*)d_in[13];
    const float* bf2 = (const float*)d_in[14];
    float* out = (float*)d_out;

    unsigned int* tmax = (unsigned int*)(ws + TMAX_OFF);
    float* qw1  = ws + QW1_OFF;
    float* qw2  = ws + QW2_OFF;
    float* qwf1 = ws + QWF1_OFF;
    float* qwf2 = ws + QWF2_OFF;
    float* h1 = ws + H1_OFF;
    float* y2 = ws + Y2_OFF;
    float* h2 = ws + H2_OFF;
    float* y3 = ws + Y3_OFF;

    hipMemsetAsync(ws + STATS_BEG, 0, (STATS_END - STATS_BEG) * sizeof(float), stream);

    absmax_k<<<74, 256, 0, stream>>>(w1, w2, wf1, wf2, tmax);
    quant_k<<<4, 256, 0, stream>>>(w1, qw1, 800, tmax, 0);
    quant_k<<<200, 256, 0, stream>>>(w2, qw2, 51200, tmax, 1);
    quant_k<<<2048, 256, 0, stream>>>(wf1, qwf1, 524288, tmax, 2);
    quant_k<<<20, 256, 0, stream>>>(wf2, qwf2, 5120, tmax, 3);

    conv1_stats_k<<<dim3(384, 32), 256, 0, stream>>>(x, qw1, ws + SUM1_OFF, ws + SSQ1_OFF);
    bn_fin_k<<<1, 256, 0, stream>>>(ws + SUM1_OFF, ws + SSQ1_OFF, g1, be1,
                                    ws + SC1_OFF, ws + SH1_OFF, 1.f / 2359296.f, 32);
    conv1_pool_k<<<dim3(192, 32), 256, 0, stream>>>(x, qw1, ws + SC1_OFF, ws + SH1_OFF, h1);

    conv2_k<<<dim3(512, 2), 256, 0, stream>>>(h1, qw2, y2, ws + SUM2_OFF, ws + SSQ2_OFF);
    bn_fin_k<<<1, 256, 0, stream>>>(ws + SUM2_OFF, ws + SSQ2_OFF, g2, be2,
                                    ws + SC2_OFF, ws + SH2_OFF, 1.f / 262144.f, 64);
    pool2_k<<<16384, 256, 0, stream>>>(y2, ws + SC2_OFF, ws + SH2_OFF, h2);

    fc1_k<<<dim3(64, 8), 256, 0, stream>>>(h2, qwf1, y3);
    bn3_stats_k<<<512, 256, 0, stream>>>(y3, ws + SUM3_OFF, ws + SSQ3_OFF);
    bn_fin_k<<<2, 256, 0, stream>>>(ws + SUM3_OFF, ws + SSQ3_OFF, g3, be3,
                                    ws + SC3_OFF, ws + SH3_OFF, 1.f / 4096.f, 512);

    fc2_k<<<64, 256, 0, stream>>>(y3, ws + SC3_OFF, ws + SH3_OFF, qwf2, bf2, out);
}

// Round 5
// 458.897 us; speedup vs baseline: 5.3880x; 1.9830x over previous
//
#include <hip/hip_runtime.h>

#define TID ((int)threadIdx.x)
typedef unsigned short u16;
typedef short short8 __attribute__((ext_vector_type(8)));
typedef float f32x4 __attribute__((ext_vector_type(4)));

__device__ __forceinline__ u16 f2b(float f) {
    unsigned int x = __float_as_uint(f);
    return (u16)((x + 0x7fffu + ((x >> 16) & 1u)) >> 16);
}
__device__ __forceinline__ float b2f(u16 u) {
    return __uint_as_float(((unsigned int)u) << 16);
}

// ---------------- workspace layout (BYTE offsets) ----------------
static constexpr size_t OFF_QW1   = 0;         // 800 f32 [32][25]
static constexpr size_t OFF_QWF2  = 3200;      // 5120 f32 [10][512]
static constexpr size_t OFF_TMAX  = 23680;     // 4 uint
static constexpr size_t OFF_SUM1  = 23808, OFF_SSQ1 = 23936, OFF_SC1 = 24064, OFF_SH1 = 24192;
static constexpr size_t OFF_SUM2  = 24320, OFF_SSQ2 = 24576, OFF_SC2 = 24832, OFF_SH2 = 25088;
static constexpr size_t OFF_SUM3  = 25344, OFF_SSQ3 = 27392, OFF_SC3 = 29440, OFF_SH3 = 31488;
static constexpr size_t STATS_END = 33536;
static constexpr size_t OFF_QW2C  = 33792;     // bf16 [25 shift][64 oc][32 ic] = 102400 B
static constexpr size_t OFF_QWF1C = 136192;    // bf16 [512][1024] = 1048576 B
static constexpr size_t OFF_H1C   = 1184768;   // bf16 [4096][12][12][32] = 37748736 B
static constexpr size_t OFF_Y2C   = 38933504;  // bf16 [4096][64 pos][64 oc]? -> [n][oc][64 pos] = 33554432 B
static constexpr size_t OFF_H2C   = 72487936;  // bf16 [4096][1024] = 8388608 B
static constexpr size_t OFF_Y3    = 80876544;  // f32 [512][4096] = 8388608 B
// total ~89.3 MB

// ---------------- abs-max of the 4 weight tensors ----------------
__global__ __launch_bounds__(256) void absmax_k(const float* w1, const float* w2,
                                                const float* wf1, const float* wf2,
                                                unsigned int* tmaxbits) {
    int bid = blockIdx.x;
    int b, lb, nb; const float* src; long n;
    if (bid < 1)       { b = 0; src = w1;  n = 800;    lb = bid;      nb = 1;  }
    else if (bid < 9)  { b = 1; src = w2;  n = 51200;  lb = bid - 1;  nb = 8;  }
    else if (bid < 73) { b = 2; src = wf1; n = 524288; lb = bid - 9;  nb = 64; }
    else               { b = 3; src = wf2; n = 5120;   lb = bid - 73; nb = 1;  }
    float m = 0.f;
    for (long i = (long)lb * 256 + TID; i < n; i += (long)nb * 256)
        m = fmaxf(m, fabsf(src[i]));
    __shared__ float red[256];
    red[TID] = m; __syncthreads();
    for (int s = 128; s > 0; s >>= 1) {
        if (TID < s) red[TID] = fmaxf(red[TID], red[TID + s]);
        __syncthreads();
    }
    if (TID == 0) atomicMax(&tmaxbits[b], __float_as_uint(red[0]));
}

// ---------------- quantizers ----------------
__global__ __launch_bounds__(256) void quant_w1_k(const float* w, float* q,
                                                  const unsigned int* tmax) {
    int i = blockIdx.x * 256 + TID; if (i >= 800) return;
    float t = 0.05f * __uint_as_float(tmax[0]);
    float v = w[i];
    q[i] = (v > t) ? 1.f : ((v < -t) ? -1.f : 0.f);
}
__global__ __launch_bounds__(256) void quant_wf2_k(const float* w, float* q,
                                                   const unsigned int* tmax) {
    int i = blockIdx.x * 256 + TID; if (i >= 5120) return;
    float t = 0.05f * __uint_as_float(tmax[3]);
    float v = w[i];
    q[i] = (v > t) ? 1.f : ((v < -t) ? -1.f : 0.f);
}
// w2 [oc][ic][5][5] -> qw2c bf16 [sh][oc][ic]
__global__ __launch_bounds__(256) void quant_w2c_k(const float* w, u16* q,
                                                   const unsigned int* tmax) {
    int i = blockIdx.x * 256 + TID; if (i >= 51200) return;
    float t = 0.05f * __uint_as_float(tmax[1]);
    int ic = i & 31, oc = (i >> 5) & 63, sh = i >> 11;   // 51200 = 25*2048
    float v = w[(oc * 32 + ic) * 25 + sh];
    q[i] = f2b((v > t) ? 1.f : ((v < -t) ? -1.f : 0.f));
}
// wf1 [512][1024] -> bf16 same layout
__global__ __launch_bounds__(256) void quant_wf1c_k(const float* w, u16* q,
                                                    const unsigned int* tmax) {
    int i = blockIdx.x * 256 + TID; if (i >= 524288) return;
    float t = 0.05f * __uint_as_float(tmax[2]);
    float v = w[i];
    q[i] = f2b((v > t) ? 1.f : ((v < -t) ? -1.f : 0.f));
}

// ---------------- conv1 pass A: stats only (fp32). thread = (n, oy), 24 outputs ----------------
__global__ __launch_bounds__(256) void conv1_stats_k(const float* __restrict__ x,
                                                     const float* __restrict__ qw1,
                                                     float* sum, float* ssq) {
    int c = blockIdx.y;
    __shared__ float wl[25];
    __shared__ float r1[256], r2[256];
    if (TID < 25) wl[TID] = qw1[c * 25 + TID];
    __syncthreads();
    int p = blockIdx.x * 256 + TID;          // < 4096*24 (grid.x = 384)
    int n = p / 24, oy = p % 24;
    const float* xb = x + n * 784 + oy * 28;
    float acc[24] = {};
    #pragma unroll
    for (int r = 0; r < 5; r++) {
        float rr[28];
        const float4* rp = reinterpret_cast<const float4*>(xb + r * 28);
        #pragma unroll
        for (int qq = 0; qq < 7; qq++) {
            float4 v = rp[qq];
            rr[qq * 4 + 0] = v.x; rr[qq * 4 + 1] = v.y; rr[qq * 4 + 2] = v.z; rr[qq * 4 + 3] = v.w;
        }
        #pragma unroll
        for (int kx = 0; kx < 5; kx++) {
            float wv = wl[r * 5 + kx];
            #pragma unroll
            for (int ox = 0; ox < 24; ox++) acc[ox] = fmaf(rr[ox + kx], wv, acc[ox]);
        }
    }
    float s = 0.f, s2 = 0.f;
    #pragma unroll
    for (int ox = 0; ox < 24; ox++) { s += acc[ox]; s2 += acc[ox] * acc[ox]; }
    r1[TID] = s; r2[TID] = s2; __syncthreads();
    for (int st = 128; st > 0; st >>= 1) {
        if (TID < st) { r1[TID] += r1[TID + st]; r2[TID] += r2[TID + st]; }
        __syncthreads();
    }
    if (TID == 0) { atomicAdd(&sum[c], r1[0]); atomicAdd(&ssq[c], r2[0]); }
}

// ---------------- BN finalize ----------------
__global__ void bn_fin_k(const float* sum, const float* ssq, const float* g,
                         const float* be, float* sc, float* sh, float inv_cnt, int C) {
    int c = blockIdx.x * 256 + TID;
    if (c >= C) return;
    float m = sum[c] * inv_cnt;
    float v = ssq[c] * inv_cnt - m * m;
    float s = g[c] / sqrtf(v + 1e-5f);
    sc[c] = s; sh[c] = be[c] - m * s;
}

// ---------------- conv1 pass B: thread = pooled pixel (n,py,px), ALL 32 ch; h1c bf16 NHWC ----------------
__global__ __launch_bounds__(256) void conv1_pool_k(const float* __restrict__ x,
                                                    const float* __restrict__ qw1,
                                                    const float* sc, const float* sh,
                                                    u16* __restrict__ h1c) {
    __shared__ float wl[800];
    __shared__ float scs[32], shs[32];
    for (int i = TID; i < 800; i += 256) wl[i] = qw1[i];
    if (TID < 32) { scs[TID] = sc[TID]; shs[TID] = sh[TID]; }
    __syncthreads();
    int p = blockIdx.x * 256 + TID;          // < 4096*144 (grid.x = 2304)
    int n = p / 144, hw = p % 144;
    int py = hw / 12, px = hw % 12;
    const float* xb = x + n * 784 + (2 * py) * 28 + 2 * px;
    float patch[6][6];
    #pragma unroll
    for (int r = 0; r < 6; r++)
        #pragma unroll
        for (int cq = 0; cq < 6; cq++) patch[r][cq] = xb[r * 28 + cq];
    u16 o[32];
    for (int c = 0; c < 32; c++) {
        float a00 = 0.f, a01 = 0.f, a10 = 0.f, a11 = 0.f;
        const float* wr = &wl[c * 25];
        #pragma unroll
        for (int ky = 0; ky < 5; ky++)
            #pragma unroll
            for (int kx = 0; kx < 5; kx++) {
                float w = wr[ky * 5 + kx];
                a00 = fmaf(patch[ky][kx],     w, a00);
                a01 = fmaf(patch[ky][kx + 1], w, a01);
                a10 = fmaf(patch[ky + 1][kx],     w, a10);
                a11 = fmaf(patch[ky + 1][kx + 1], w, a11);
            }
        float scl = scs[c], shf = shs[c];
        float v = fmaxf(fmaxf(fmaxf(a00 * scl + shf, a01 * scl + shf),
                              fmaxf(a10 * scl + shf, a11 * scl + shf)), 0.f);
        o[c] = f2b(v);
    }
    float4* dst = reinterpret_cast<float4*>(h1c + (size_t)p * 32);
    const float4* ov = reinterpret_cast<const float4*>(o);
    #pragma unroll
    for (int qq = 0; qq < 4; qq++) dst[qq] = ov[qq];
}

// ---------------- conv2: MFMA implicit conv. block = 8 samples; wave = 16 ocs ----------------
// h1c: bf16 [n][12][12][32]; qw2c: bf16 [sh][oc][ic]; y2c: bf16 [n][oc][64 pos]
__global__ __launch_bounds__(256) void conv2_k(const u16* __restrict__ h1c,
                                               const u16* __restrict__ qw2c,
                                               u16* __restrict__ y2c,
                                               float* sum, float* ssq) {
    // LDS per sample: 12 rows * (12*64B + 16B pad) = 9408 B; 2 buffers
    __shared__ float4 hsm4[1176];            // 18816 B
    char* hsraw = (char*)hsm4;
    int n0 = blockIdx.x * 8;                 // grid.x = 512
    int l = TID & 63, wv = TID >> 6;
    int oc0 = wv * 16;
    int lm = l & 15, lr = (l >> 3) & 1, ox = l & 7, bq = l >> 4;
    // B fragments: 25 shifts, this wave's 16 ocs, held in VGPRs
    short8 bw[25];
    #pragma unroll
    for (int sh = 0; sh < 25; sh++)
        bw[sh] = *reinterpret_cast<const short8*>(qw2c + ((size_t)sh * 64 + oc0 + lm) * 32 + bq * 8);
    // per-lane LDS read bases per kx (swizzled channels-last)
    int xy[5];
    #pragma unroll
    for (int kx = 0; kx < 5; kx++) {
        int xx = ox + kx;
        xy[kx] = lr * 784 + xx * 64 + ((bq ^ (xx & 3)) * 16);
    }
    float sacc = 0.f, s2acc = 0.f;
    // stage sample 0
    {
        const float4* src = reinterpret_cast<const float4*>(h1c + (size_t)n0 * 4608);
        #pragma unroll
        for (int k = 0; k < 3; k++) {
            if (k < 2 || TID < 64) {
                int i = TID + k * 256;
                int pix = i >> 2, b = i & 3;
                int y = pix / 12, xx = pix - y * 12;
                *reinterpret_cast<float4*>(hsraw + y * 784 + xx * 64 + ((b ^ (xx & 3)) * 16)) = src[i];
            }
        }
    }
    #pragma unroll 1
    for (int s = 0; s < 8; s++) {
        __syncthreads();
        if (s < 7) {
            const float4* src = reinterpret_cast<const float4*>(h1c + (size_t)(n0 + s + 1) * 4608);
            char* dst = hsraw + ((s + 1) & 1) * 9408;
            #pragma unroll
            for (int k = 0; k < 3; k++) {
                if (k < 2 || TID < 64) {
                    int i = TID + k * 256;
                    int pix = i >> 2, b = i & 3;
                    int y = pix / 12, xx = pix - y * 12;
                    *reinterpret_cast<float4*>(dst + y * 784 + xx * 64 + ((b ^ (xx & 3)) * 16)) = src[i];
                }
            }
        }
        const char* hb = hsraw + (s & 1) * 9408;
        f32x4 acc[4] = {{0.f,0.f,0.f,0.f},{0.f,0.f,0.f,0.f},{0.f,0.f,0.f,0.f},{0.f,0.f,0.f,0.f}};
        #pragma unroll
        for (int ky = 0; ky < 5; ky++)
            #pragma unroll
            for (int kx = 0; kx < 5; kx++) {
                const int sh = ky * 5 + kx;
                #pragma unroll
                for (int mt = 0; mt < 4; mt++) {
                    short8 a = *reinterpret_cast<const short8*>(hb + xy[kx] + (mt * 2 + ky) * 784);
                    acc[mt] = __builtin_amdgcn_mfma_f32_16x16x32_bf16(a, bw[sh], acc[mt], 0, 0, 0);
                }
            }
        int n = n0 + s;
        #pragma unroll
        for (int mt = 0; mt < 4; mt++) {
            float v0 = acc[mt][0], v1 = acc[mt][1], v2 = acc[mt][2], v3 = acc[mt][3];
            sacc += v0 + v1 + v2 + v3;
            s2acc += v0 * v0 + v1 * v1 + v2 * v2 + v3 * v3;
            ushort4 u = make_ushort4(f2b(v0), f2b(v1), f2b(v2), f2b(v3));
            *reinterpret_cast<ushort4*>(y2c + (size_t)n * 4096 + (oc0 + lm) * 64 + mt * 16 + bq * 4) = u;
        }
    }
    // stats: lanes l, l^16, l^32, l^48 share oc = oc0+lm
    sacc  += __shfl_xor(sacc, 16);  sacc  += __shfl_xor(sacc, 32);
    s2acc += __shfl_xor(s2acc, 16); s2acc += __shfl_xor(s2acc, 32);
    if (l < 16) { atomicAdd(&sum[oc0 + l], sacc); atomicAdd(&ssq[oc0 + l], s2acc); }
}

// ---------------- pool2: BN + relu + maxpool; y2c bf16 [n][oc][64] -> h2c bf16 [n][1024] ----------------
__global__ __launch_bounds__(256) void pool2_k(const u16* __restrict__ y2c,
                                               const float* sc, const float* sh,
                                               u16* __restrict__ h2c) {
    int i = blockIdx.x * 256 + TID;          // < 4096*1024 (grid.x = 16384)
    int px = i & 3, py = (i >> 2) & 3, oc = (i >> 4) & 63, n = i >> 10;
    size_t base = (size_t)n * 4096 + oc * 64 + (2 * py) * 8 + 2 * px;
    float s = sc[oc], t = sh[oc];
    float a = b2f(y2c[base])     * s + t;
    float b = b2f(y2c[base + 1]) * s + t;
    float c = b2f(y2c[base + 8]) * s + t;
    float d = b2f(y2c[base + 9]) * s + t;
    float m = fmaxf(fmaxf(fmaxf(fmaxf(0.f, a), b), c), d);
    h2c[i] = f2b(m);                          // i == n*1024 + oc*16 + py*4 + px
}

// ---------------- fc1: MFMA GEMM [4096x1024]x[512x1024]^T -> y3T f32 [512][4096] ----------------
__global__ __launch_bounds__(256) void fc1_k(const u16* __restrict__ h2c,
                                             const u16* __restrict__ qwf1c,
                                             float* __restrict__ y3T) {
    __shared__ float4 Asm[576], Bsm[576];    // each 9216 B = 64 rows x 72 u16 (pad 8)
    u16* AsU = (u16*)Asm; u16* BsU = (u16*)Bsm;
    int m0 = blockIdx.x * 64, j0 = blockIdx.y * 64;
    int l = TID & 63, wv = TID >> 6;
    int lm = l & 15, q = l >> 4;
    int r0 = TID >> 3, c0 = TID & 7;
    f32x4 acc[4] = {{0.f,0.f,0.f,0.f},{0.f,0.f,0.f,0.f},{0.f,0.f,0.f,0.f},{0.f,0.f,0.f,0.f}};
    #pragma unroll 1
    for (int kc = 0; kc < 16; kc++) {
        int kk = kc * 64;
        if (kc) __syncthreads();
        #pragma unroll
        for (int i = 0; i < 2; i++) {
            int r = i * 32 + r0;
            *reinterpret_cast<float4*>(AsU + r * 72 + c0 * 8) =
                *reinterpret_cast<const float4*>(h2c + (size_t)(m0 + r) * 1024 + kk + c0 * 8);
            *reinterpret_cast<float4*>(BsU + r * 72 + c0 * 8) =
                *reinterpret_cast<const float4*>(qwf1c + (size_t)(j0 + r) * 1024 + kk + c0 * 8);
        }
        __syncthreads();
        #pragma unroll
        for (int half = 0; half < 2; half++) {
            short8 b = *reinterpret_cast<const short8*>(BsU + (wv * 16 + lm) * 72 + half * 32 + q * 8);
            #pragma unroll
            for (int mt = 0; mt < 4; mt++) {
                short8 a = *reinterpret_cast<const short8*>(AsU + (mt * 16 + lm) * 72 + half * 32 + q * 8);
                acc[mt] = __builtin_amdgcn_mfma_f32_16x16x32_bf16(a, b, acc[mt], 0, 0, 0);
            }
        }
    }
    #pragma unroll
    for (int mt = 0; mt < 4; mt++)
        *reinterpret_cast<f32x4*>(y3T + (size_t)(j0 + wv * 16 + lm) * 4096 + m0 + mt * 16 + q * 4) = acc[mt];
}

// ---------------- bn3 stats ----------------
__global__ __launch_bounds__(256) void bn3_stats_k(const float* __restrict__ y3T,
                                                   float* sum, float* ssq) {
    int j = blockIdx.x;
    __shared__ float r1[256], r2[256];
    float s = 0.f, s2 = 0.f;
    for (int n = TID; n < 4096; n += 256) {
        float v = y3T[(size_t)j * 4096 + n];
        s += v; s2 += v * v;
    }
    r1[TID] = s; r2[TID] = s2; __syncthreads();
    for (int st = 128; st > 0; st >>= 1) {
        if (TID < st) { r1[TID] += r1[TID + st]; r2[TID] += r2[TID + st]; }
        __syncthreads();
    }
    if (TID == 0) { sum[j] = r1[0]; ssq[j] = r2[0]; }
}

// ---------------- fc2: K-sliced; block = 64 n x 4 k-slices; grid.x = 64 ----------------
__global__ __launch_bounds__(256) void fc2_k(const float* __restrict__ y3T,
                                             const float* sc, const float* sh,
                                             const float* __restrict__ qwf2,
                                             const float* bf2, float* __restrict__ out) {
    __shared__ float wlds[5120];
    __shared__ float part[3][640];
    for (int i = TID; i < 5120; i += 256) wlds[i] = qwf2[i];
    __syncthreads();
    int nl = TID & 63, ks = TID >> 6;
    int n = blockIdx.x * 64 + nl;
    float acc[10] = {};
    for (int k = ks * 128; k < ks * 128 + 128; k++) {
        float v = fmaxf(y3T[(size_t)k * 4096 + n] * sc[k] + sh[k], 0.f);
        #pragma unroll
        for (int o = 0; o < 10; o++) acc[o] = fmaf(v, wlds[o * 512 + k], acc[o]);
    }
    if (ks > 0) {
        #pragma unroll
        for (int o = 0; o < 10; o++) part[ks - 1][o * 64 + nl] = acc[o];
    }
    __syncthreads();
    if (ks == 0) {
        #pragma unroll
        for (int o = 0; o < 10; o++)
            out[n * 10 + o] = acc[o] + part[0][o * 64 + nl] + part[1][o * 64 + nl]
                              + part[2][o * 64 + nl] + bf2[o];
    }
}

extern "C" void kernel_launch(void* const* d_in, const int* in_sizes, int n_in,
                              void* d_out, int out_size, void* d_ws, size_t ws_size,
                              hipStream_t stream) {
    char* wsb = (char*)d_ws;
    const float* x   = (const float*)d_in[0];
    const float* w1  = (const float*)d_in[1];
    // b1/b2/bf1 cancel under training-mode BN
    const float* g1  = (const float*)d_in[3];
    const float* be1 = (const float*)d_in[4];
    const float* w2  = (const float*)d_in[5];
    const float* g2  = (const float*)d_in[7];
    const float* be2 = (const float*)d_in[8];
    const float* wf1 = (const float*)d_in[9];
    const float* g3  = (const float*)d_in[11];
    const float* be3 = (const float*)d_in[12];
    const float* wf2 = (const float*)d_in[13];
    const float* bf2 = (const float*)d_in[14];
    float* out = (float*)d_out;

    unsigned int* tmax = (unsigned int*)(wsb + OFF_TMAX);
    float* qw1   = (float*)(wsb + OFF_QW1);
    float* qwf2  = (float*)(wsb + OFF_QWF2);
    u16*   qw2c  = (u16*)(wsb + OFF_QW2C);
    u16*   qwf1c = (u16*)(wsb + OFF_QWF1C);
    u16*   h1c   = (u16*)(wsb + OFF_H1C);
    u16*   y2c   = (u16*)(wsb + OFF_Y2C);
    u16*   h2c   = (u16*)(wsb + OFF_H2C);
    float* y3    = (float*)(wsb + OFF_Y3);

    float* sum1 = (float*)(wsb + OFF_SUM1); float* ssq1 = (float*)(wsb + OFF_SSQ1);
    float* sc1  = (float*)(wsb + OFF_SC1);  float* sh1  = (float*)(wsb + OFF_SH1);
    float* sum2 = (float*)(wsb + OFF_SUM2); float* ssq2 = (float*)(wsb + OFF_SSQ2);
    float* sc2  = (float*)(wsb + OFF_SC2);  float* sh2  = (float*)(wsb + OFF_SH2);
    float* sum3 = (float*)(wsb + OFF_SUM3); float* ssq3 = (float*)(wsb + OFF_SSQ3);
    float* sc3  = (float*)(wsb + OFF_SC3);  float* sh3  = (float*)(wsb + OFF_SH3);

    hipMemsetAsync(wsb + OFF_TMAX, 0, STATS_END - OFF_TMAX, stream);

    absmax_k<<<74, 256, 0, stream>>>(w1, w2, wf1, wf2, tmax);
    quant_w1_k<<<4, 256, 0, stream>>>(w1, qw1, tmax);
    quant_w2c_k<<<200, 256, 0, stream>>>(w2, qw2c, tmax);
    quant_wf1c_k<<<2048, 256, 0, stream>>>(wf1, qwf1c, tmax);
    quant_wf2_k<<<20, 256, 0, stream>>>(wf2, qwf2, tmax);

    conv1_stats_k<<<dim3(384, 32), 256, 0, stream>>>(x, qw1, sum1, ssq1);
    bn_fin_k<<<1, 256, 0, stream>>>(sum1, ssq1, g1, be1, sc1, sh1, 1.f / 2359296.f, 32);
    conv1_pool_k<<<2304, 256, 0, stream>>>(x, qw1, sc1, sh1, h1c);

    conv2_k<<<512, 256, 0, stream>>>(h1c, qw2c, y2c, sum2, ssq2);
    bn_fin_k<<<1, 256, 0, stream>>>(sum2, ssq2, g2, be2, sc2, sh2, 1.f / 262144.f, 64);
    pool2_k<<<16384, 256, 0, stream>>>(y2c, sc2, sh2, h2c);

    fc1_k<<<dim3(64, 8), 256, 0, stream>>>(h2c, qwf1c, y3);
    bn3_stats_k<<<512, 256, 0, stream>>>(y3, sum3, ssq3);
    bn_fin_k<<<2, 256, 0, stream>>>(sum3, ssq3, g3, be3, sc3, sh3, 1.f / 4096.f, 512);

    fc2_k<<<64, 256, 0, stream>>>(y3, sc3, sh3, qwf2, bf2, out);
}

// Round 6
// 344.810 us; speedup vs baseline: 7.1707x; 1.3309x over previous
//
#include <hip/hip_runtime.h>

#define TID ((int)threadIdx.x)
typedef unsigned short u16;
typedef short short8 __attribute__((ext_vector_type(8)));
typedef float f32x4 __attribute__((ext_vector_type(4)));

__device__ __forceinline__ u16 f2b(float f) {
    unsigned int x = __float_as_uint(f);
    return (u16)((x + 0x7fffu + ((x >> 16) & 1u)) >> 16);
}
__device__ __forceinline__ float b2f(u16 u) {
    return __uint_as_float(((unsigned int)u) << 16);
}

// ---------------- workspace layout (BYTE offsets) ----------------
static constexpr size_t OFF_QW1   = 0;         // 800 f32 [32][25]
static constexpr size_t OFF_QWF2  = 3200;      // 5120 f32 [10][512]
static constexpr size_t OFF_TMAX  = 23680;     // 4 uint
static constexpr size_t OFF_SUM1  = 23808, OFF_SSQ1 = 23936, OFF_SC1 = 24064, OFF_SH1 = 24192;
static constexpr size_t OFF_SUM2  = 24320, OFF_SSQ2 = 24576, OFF_SC2 = 24832, OFF_SH2 = 25088;
static constexpr size_t OFF_SUM3  = 25344, OFF_SSQ3 = 27392, OFF_SC3 = 29440, OFF_SH3 = 31488;
static constexpr size_t STATS_END = 33536;
static constexpr size_t OFF_QW2C  = 33792;     // bf16 [25 shift][64 oc][32 ic] = 102400 B
static constexpr size_t OFF_QWF1C = 136192;    // bf16 [512][1024] = 1048576 B
static constexpr size_t OFF_H1C   = 1184768;   // bf16 [4096][12][12][32] = 37748736 B
static constexpr size_t OFF_Y2C   = 38933504;  // bf16 [n][oc][64 pos] = 33554432 B
static constexpr size_t OFF_H2C   = 72487936;  // bf16 [4096][1024] = 8388608 B
static constexpr size_t OFF_Y3    = 80876544;  // f32 [512][4096] = 8388608 B
// total ~89.3 MB

// ---------------- abs-max of the 4 weight tensors ----------------
__global__ __launch_bounds__(256) void absmax_k(const float* w1, const float* w2,
                                                const float* wf1, const float* wf2,
                                                unsigned int* tmaxbits) {
    int bid = blockIdx.x;
    int b, lb, nb; const float* src; long n;
    if (bid < 1)       { b = 0; src = w1;  n = 800;    lb = bid;      nb = 1;  }
    else if (bid < 9)  { b = 1; src = w2;  n = 51200;  lb = bid - 1;  nb = 8;  }
    else if (bid < 73) { b = 2; src = wf1; n = 524288; lb = bid - 9;  nb = 64; }
    else               { b = 3; src = wf2; n = 5120;   lb = bid - 73; nb = 1;  }
    float m = 0.f;
    for (long i = (long)lb * 256 + TID; i < n; i += (long)nb * 256)
        m = fmaxf(m, fabsf(src[i]));
    __shared__ float red[256];
    red[TID] = m; __syncthreads();
    for (int s = 128; s > 0; s >>= 1) {
        if (TID < s) red[TID] = fmaxf(red[TID], red[TID + s]);
        __syncthreads();
    }
    if (TID == 0) atomicMax(&tmaxbits[b], __float_as_uint(red[0]));
}

// ---------------- quantizers ----------------
__global__ __launch_bounds__(256) void quant_w1_k(const float* w, float* q,
                                                  const unsigned int* tmax) {
    int i = blockIdx.x * 256 + TID; if (i >= 800) return;
    float t = 0.05f * __uint_as_float(tmax[0]);
    float v = w[i];
    q[i] = (v > t) ? 1.f : ((v < -t) ? -1.f : 0.f);
}
__global__ __launch_bounds__(256) void quant_wf2_k(const float* w, float* q,
                                                   const unsigned int* tmax) {
    int i = blockIdx.x * 256 + TID; if (i >= 5120) return;
    float t = 0.05f * __uint_as_float(tmax[3]);
    float v = w[i];
    q[i] = (v > t) ? 1.f : ((v < -t) ? -1.f : 0.f);
}
// w2 [oc][ic][5][5] -> qw2c bf16 [sh][oc][ic]
__global__ __launch_bounds__(256) void quant_w2c_k(const float* w, u16* q,
                                                   const unsigned int* tmax) {
    int i = blockIdx.x * 256 + TID; if (i >= 51200) return;
    float t = 0.05f * __uint_as_float(tmax[1]);
    int ic = i & 31, oc = (i >> 5) & 63, sh = i >> 11;   // 51200 = 25*2048
    float v = w[(oc * 32 + ic) * 25 + sh];
    q[i] = f2b((v > t) ? 1.f : ((v < -t) ? -1.f : 0.f));
}
// wf1 [512][1024] -> bf16 same layout
__global__ __launch_bounds__(256) void quant_wf1c_k(const float* w, u16* q,
                                                    const unsigned int* tmax) {
    int i = blockIdx.x * 256 + TID; if (i >= 524288) return;
    float t = 0.05f * __uint_as_float(tmax[2]);
    float v = w[i];
    q[i] = f2b((v > t) ? 1.f : ((v < -t) ? -1.f : 0.f));
}

// ---------------- conv1 pass A: stats, ALL 32 channels per thread ----------------
// thread = (n, oy, half): 12 outputs from a 5x16 register patch; loop 32 channels.
__global__ __launch_bounds__(256) void conv1_stats_k(const float* __restrict__ x,
                                                     const float* __restrict__ qw1,
                                                     float* sum, float* ssq) {
    __shared__ float wl[800];
    __shared__ float psum[128], pssq[128];   // [4 waves][32 ch]
    for (int i = TID; i < 800; i += 256) wl[i] = qw1[i];
    __syncthreads();
    int p = blockIdx.x * 256 + TID;          // < 4096*48 exactly (grid.x = 768)
    int n = p / 48, rem = p % 48, oy = rem >> 1, half = rem & 1;
    int l = TID & 63, wv = TID >> 6;
    const float* xb = x + n * 784 + oy * 28 + half * 12;
    float rr[5][16];
    #pragma unroll
    for (int r = 0; r < 5; r++) {
        const float4* rp = reinterpret_cast<const float4*>(xb + r * 28);
        #pragma unroll
        for (int qq = 0; qq < 4; qq++) {
            float4 v = rp[qq];
            rr[r][qq * 4 + 0] = v.x; rr[r][qq * 4 + 1] = v.y;
            rr[r][qq * 4 + 2] = v.z; rr[r][qq * 4 + 3] = v.w;
        }
    }
    #pragma unroll 1
    for (int c = 0; c < 32; c++) {
        const float* wr = &wl[c * 25];
        float acc[12] = {};
        #pragma unroll
        for (int ky = 0; ky < 5; ky++)
            #pragma unroll
            for (int kx = 0; kx < 5; kx++) {
                float w = wr[ky * 5 + kx];
                #pragma unroll
                for (int ox = 0; ox < 12; ox++)
                    acc[ox] = fmaf(rr[ky][ox + kx], w, acc[ox]);
            }
        float sc = 0.f, s2c = 0.f;
        #pragma unroll
        for (int ox = 0; ox < 12; ox++) { sc += acc[ox]; s2c += acc[ox] * acc[ox]; }
        #pragma unroll
        for (int m = 1; m < 64; m <<= 1) {
            sc  += __shfl_xor(sc,  m);
            s2c += __shfl_xor(s2c, m);
        }
        if (l == 0) { psum[wv * 32 + c] = sc; pssq[wv * 32 + c] = s2c; }
    }
    __syncthreads();
    if (TID < 32) {
        float ts = psum[TID] + psum[32 + TID] + psum[64 + TID] + psum[96 + TID];
        float t2 = pssq[TID] + pssq[32 + TID] + pssq[64 + TID] + pssq[96 + TID];
        atomicAdd(&sum[TID], ts); atomicAdd(&ssq[TID], t2);
    }
}

// ---------------- BN finalize ----------------
__global__ void bn_fin_k(const float* sum, const float* ssq, const float* g,
                         const float* be, float* sc, float* sh, float inv_cnt, int C) {
    int c = blockIdx.x * 256 + TID;
    if (c >= C) return;
    float m = sum[c] * inv_cnt;
    float v = ssq[c] * inv_cnt - m * m;
    float s = g[c] / sqrtf(v + 1e-5f);
    sc[c] = s; sh[c] = be[c] - m * s;
}

// ---------------- conv1 pass B: thread = pooled pixel (n,py,px), ALL 32 ch; h1c bf16 NHWC ----------------
__global__ __launch_bounds__(256) void conv1_pool_k(const float* __restrict__ x,
                                                    const float* __restrict__ qw1,
                                                    const float* sc, const float* sh,
                                                    u16* __restrict__ h1c) {
    __shared__ float wl[800];
    __shared__ float scs[32], shs[32];
    for (int i = TID; i < 800; i += 256) wl[i] = qw1[i];
    if (TID < 32) { scs[TID] = sc[TID]; shs[TID] = sh[TID]; }
    __syncthreads();
    int p = blockIdx.x * 256 + TID;          // < 4096*144 (grid.x = 2304)
    int n = p / 144, hw = p % 144;
    int py = hw / 12, px = hw % 12;
    const float* xb = x + n * 784 + (2 * py) * 28 + 2 * px;
    float patch[6][6];
    #pragma unroll
    for (int r = 0; r < 6; r++)
        #pragma unroll
        for (int cq = 0; cq < 6; cq++) patch[r][cq] = xb[r * 28 + cq];
    u16 o[32];
    for (int c = 0; c < 32; c++) {
        float a00 = 0.f, a01 = 0.f, a10 = 0.f, a11 = 0.f;
        const float* wr = &wl[c * 25];
        #pragma unroll
        for (int ky = 0; ky < 5; ky++)
            #pragma unroll
            for (int kx = 0; kx < 5; kx++) {
                float w = wr[ky * 5 + kx];
                a00 = fmaf(patch[ky][kx],     w, a00);
                a01 = fmaf(patch[ky][kx + 1], w, a01);
                a10 = fmaf(patch[ky + 1][kx],     w, a10);
                a11 = fmaf(patch[ky + 1][kx + 1], w, a11);
            }
        float scl = scs[c], shf = shs[c];
        float v = fmaxf(fmaxf(fmaxf(a00 * scl + shf, a01 * scl + shf),
                              fmaxf(a10 * scl + shf, a11 * scl + shf)), 0.f);
        o[c] = f2b(v);
    }
    float4* dst = reinterpret_cast<float4*>(h1c + (size_t)p * 32);
    const float4* ov = reinterpret_cast<const float4*>(o);
    #pragma unroll
    for (int qq = 0; qq < 4; qq++) dst[qq] = ov[qq];
}

// ---------------- conv2: MFMA implicit conv. block = 8 samples; wave = 16 ocs ----------------
// h1c: bf16 [n][12][12][32]; qw2c: bf16 [sh][oc][ic]; y2c: bf16 [n][oc][64 pos]
__global__ __launch_bounds__(256) void conv2_k(const u16* __restrict__ h1c,
                                               const u16* __restrict__ qw2c,
                                               u16* __restrict__ y2c,
                                               float* sum, float* ssq) {
    // LDS per sample: 12 rows * (12*64B + 16B pad) = 9408 B; 2 buffers
    __shared__ float4 hsm4[1176];            // 18816 B
    char* hsraw = (char*)hsm4;
    int n0 = blockIdx.x * 8;                 // grid.x = 512
    int l = TID & 63, wv = TID >> 6;
    int oc0 = wv * 16;
    int lm = l & 15, lr = (l >> 3) & 1, ox = l & 7, bq = l >> 4;
    // B fragments: 25 shifts, this wave's 16 ocs, held in VGPRs
    short8 bw[25];
    #pragma unroll
    for (int sh = 0; sh < 25; sh++)
        bw[sh] = *reinterpret_cast<const short8*>(qw2c + ((size_t)sh * 64 + oc0 + lm) * 32 + bq * 8);
    // per-lane LDS read bases per kx (swizzled channels-last)
    int xy[5];
    #pragma unroll
    for (int kx = 0; kx < 5; kx++) {
        int xx = ox + kx;
        xy[kx] = lr * 784 + xx * 64 + ((bq ^ (xx & 3)) * 16);
    }
    float sacc = 0.f, s2acc = 0.f;
    // stage sample 0
    {
        const float4* src = reinterpret_cast<const float4*>(h1c + (size_t)n0 * 4608);
        #pragma unroll
        for (int k = 0; k < 3; k++) {
            if (k < 2 || TID < 64) {
                int i = TID + k * 256;
                int pix = i >> 2, b = i & 3;
                int y = pix / 12, xx = pix - y * 12;
                *reinterpret_cast<float4*>(hsraw + y * 784 + xx * 64 + ((b ^ (xx & 3)) * 16)) = src[i];
            }
        }
    }
    #pragma unroll 1
    for (int s = 0; s < 8; s++) {
        __syncthreads();
        if (s < 7) {
            const float4* src = reinterpret_cast<const float4*>(h1c + (size_t)(n0 + s + 1) * 4608);
            char* dst = hsraw + ((s + 1) & 1) * 9408;
            #pragma unroll
            for (int k = 0; k < 3; k++) {
                if (k < 2 || TID < 64) {
                    int i = TID + k * 256;
                    int pix = i >> 2, b = i & 3;
                    int y = pix / 12, xx = pix - y * 12;
                    *reinterpret_cast<float4*>(dst + y * 784 + xx * 64 + ((b ^ (xx & 3)) * 16)) = src[i];
                }
            }
        }
        const char* hb = hsraw + (s & 1) * 9408;
        f32x4 acc[4] = {{0.f,0.f,0.f,0.f},{0.f,0.f,0.f,0.f},{0.f,0.f,0.f,0.f},{0.f,0.f,0.f,0.f}};
        #pragma unroll
        for (int ky = 0; ky < 5; ky++)
            #pragma unroll
            for (int kx = 0; kx < 5; kx++) {
                const int sh = ky * 5 + kx;
                #pragma unroll
                for (int mt = 0; mt < 4; mt++) {
                    short8 a = *reinterpret_cast<const short8*>(hb + xy[kx] + (mt * 2 + ky) * 784);
                    acc[mt] = __builtin_amdgcn_mfma_f32_16x16x32_bf16(a, bw[sh], acc[mt], 0, 0, 0);
                }
            }
        int n = n0 + s;
        #pragma unroll
        for (int mt = 0; mt < 4; mt++) {
            float v0 = acc[mt][0], v1 = acc[mt][1], v2 = acc[mt][2], v3 = acc[mt][3];
            sacc += v0 + v1 + v2 + v3;
            s2acc += v0 * v0 + v1 * v1 + v2 * v2 + v3 * v3;
            ushort4 u = make_ushort4(f2b(v0), f2b(v1), f2b(v2), f2b(v3));
            *reinterpret_cast<ushort4*>(y2c + (size_t)n * 4096 + (oc0 + lm) * 64 + mt * 16 + bq * 4) = u;
        }
    }
    // stats: lanes l, l^16, l^32, l^48 share oc = oc0+lm
    sacc  += __shfl_xor(sacc, 16);  sacc  += __shfl_xor(sacc, 32);
    s2acc += __shfl_xor(s2acc, 16); s2acc += __shfl_xor(s2acc, 32);
    if (l < 16) { atomicAdd(&sum[oc0 + l], sacc); atomicAdd(&ssq[oc0 + l], s2acc); }
}

// ---------------- pool2: BN + relu + maxpool; y2c bf16 [n][oc][64] -> h2c bf16 [n][1024] ----------------
__global__ __launch_bounds__(256) void pool2_k(const u16* __restrict__ y2c,
                                               const float* sc, const float* sh,
                                               u16* __restrict__ h2c) {
    int i = blockIdx.x * 256 + TID;          // < 4096*1024 (grid.x = 16384)
    int px = i & 3, py = (i >> 2) & 3, oc = (i >> 4) & 63, n = i >> 10;
    size_t base = (size_t)n * 4096 + oc * 64 + (2 * py) * 8 + 2 * px;
    float s = sc[oc], t = sh[oc];
    float a = b2f(y2c[base])     * s + t;
    float b = b2f(y2c[base + 1]) * s + t;
    float c = b2f(y2c[base + 8]) * s + t;
    float d = b2f(y2c[base + 9]) * s + t;
    float m = fmaxf(fmaxf(fmaxf(fmaxf(0.f, a), b), c), d);
    h2c[i] = f2b(m);                          // i == n*1024 + oc*16 + py*4 + px
}

// ---------------- fc1: MFMA GEMM [4096x1024]x[512x1024]^T -> y3T f32 [512][4096] ----------------
__global__ __launch_bounds__(256) void fc1_k(const u16* __restrict__ h2c,
                                             const u16* __restrict__ qwf1c,
                                             float* __restrict__ y3T) {
    __shared__ float4 Asm[576], Bsm[576];    // each 9216 B = 64 rows x 72 u16 (pad 8)
    u16* AsU = (u16*)Asm; u16* BsU = (u16*)Bsm;
    int m0 = blockIdx.x * 64, j0 = blockIdx.y * 64;
    int l = TID & 63, wv = TID >> 6;
    int lm = l & 15, q = l >> 4;
    int r0 = TID >> 3, c0 = TID & 7;
    f32x4 acc[4] = {{0.f,0.f,0.f,0.f},{0.f,0.f,0.f,0.f},{0.f,0.f,0.f,0.f},{0.f,0.f,0.f,0.f}};
    #pragma unroll 1
    for (int kc = 0; kc < 16; kc++) {
        int kk = kc * 64;
        if (kc) __syncthreads();
        #pragma unroll
        for (int i = 0; i < 2; i++) {
            int r = i * 32 + r0;
            *reinterpret_cast<float4*>(AsU + r * 72 + c0 * 8) =
                *reinterpret_cast<const float4*>(h2c + (size_t)(m0 + r) * 1024 + kk + c0 * 8);
            *reinterpret_cast<float4*>(BsU + r * 72 + c0 * 8) =
                *reinterpret_cast<const float4*>(qwf1c + (size_t)(j0 + r) * 1024 + kk + c0 * 8);
        }
        __syncthreads();
        #pragma unroll
        for (int half = 0; half < 2; half++) {
            short8 b = *reinterpret_cast<const short8*>(BsU + (wv * 16 + lm) * 72 + half * 32 + q * 8);
            #pragma unroll
            for (int mt = 0; mt < 4; mt++) {
                short8 a = *reinterpret_cast<const short8*>(AsU + (mt * 16 + lm) * 72 + half * 32 + q * 8);
                acc[mt] = __builtin_amdgcn_mfma_f32_16x16x32_bf16(a, b, acc[mt], 0, 0, 0);
            }
        }
    }
    #pragma unroll
    for (int mt = 0; mt < 4; mt++)
        *reinterpret_cast<f32x4*>(y3T + (size_t)(j0 + wv * 16 + lm) * 4096 + m0 + mt * 16 + q * 4) = acc[mt];
}

// ---------------- bn3 stats ----------------
__global__ __launch_bounds__(256) void bn3_stats_k(const float* __restrict__ y3T,
                                                   float* sum, float* ssq) {
    int j = blockIdx.x;
    __shared__ float r1[256], r2[256];
    float s = 0.f, s2 = 0.f;
    for (int n = TID; n < 4096; n += 256) {
        float v = y3T[(size_t)j * 4096 + n];
        s += v; s2 += v * v;
    }
    r1[TID] = s; r2[TID] = s2; __syncthreads();
    for (int st = 128; st > 0; st >>= 1) {
        if (TID < st) { r1[TID] += r1[TID + st]; r2[TID] += r2[TID + st]; }
        __syncthreads();
    }
    if (TID == 0) { sum[j] = r1[0]; ssq[j] = r2[0]; }
}

// ---------------- fc2: K-sliced; block = 64 n x 4 k-slices; grid.x = 64 ----------------
__global__ __launch_bounds__(256) void fc2_k(const float* __restrict__ y3T,
                                             const float* sc, const float* sh,
                                             const float* __restrict__ qwf2,
                                             const float* bf2, float* __restrict__ out) {
    __shared__ float wlds[5120];
    __shared__ float part[3][640];
    for (int i = TID; i < 5120; i += 256) wlds[i] = qwf2[i];
    __syncthreads();
    int nl = TID & 63, ks = TID >> 6;
    int n = blockIdx.x * 64 + nl;
    float acc[10] = {};
    for (int k = ks * 128; k < ks * 128 + 128; k++) {
        float v = fmaxf(y3T[(size_t)k * 4096 + n] * sc[k] + sh[k], 0.f);
        #pragma unroll
        for (int o = 0; o < 10; o++) acc[o] = fmaf(v, wlds[o * 512 + k], acc[o]);
    }
    if (ks > 0) {
        #pragma unroll
        for (int o = 0; o < 10; o++) part[ks - 1][o * 64 + nl] = acc[o];
    }
    __syncthreads();
    if (ks == 0) {
        #pragma unroll
        for (int o = 0; o < 10; o++)
            out[n * 10 + o] = acc[o] + part[0][o * 64 + nl] + part[1][o * 64 + nl]
                              + part[2][o * 64 + nl] + bf2[o];
    }
}

extern "C" void kernel_launch(void* const* d_in, const int* in_sizes, int n_in,
                              void* d_out, int out_size, void* d_ws, size_t ws_size,
                              hipStream_t stream) {
    char* wsb = (char*)d_ws;
    const float* x   = (const float*)d_in[0];
    const float* w1  = (const float*)d_in[1];
    // b1/b2/bf1 cancel under training-mode BN
    const float* g1  = (const float*)d_in[3];
    const float* be1 = (const float*)d_in[4];
    const float* w2  = (const float*)d_in[5];
    const float* g2  = (const float*)d_in[7];
    const float* be2 = (const float*)d_in[8];
    const float* wf1 = (const float*)d_in[9];
    const float* g3  = (const float*)d_in[11];
    const float* be3 = (const float*)d_in[12];
    const float* wf2 = (const float*)d_in[13];
    const float* bf2 = (const float*)d_in[14];
    float* out = (float*)d_out;

    unsigned int* tmax = (unsigned int*)(wsb + OFF_TMAX);
    float* qw1   = (float*)(wsb + OFF_QW1);
    float* qwf2  = (float*)(wsb + OFF_QWF2);
    u16*   qw2c  = (u16*)(wsb + OFF_QW2C);
    u16*   qwf1c = (u16*)(wsb + OFF_QWF1C);
    u16*   h1c   = (u16*)(wsb + OFF_H1C);
    u16*   y2c   = (u16*)(wsb + OFF_Y2C);
    u16*   h2c   = (u16*)(wsb + OFF_H2C);
    float* y3    = (float*)(wsb + OFF_Y3);

    float* sum1 = (float*)(wsb + OFF_SUM1); float* ssq1 = (float*)(wsb + OFF_SSQ1);
    float* sc1  = (float*)(wsb + OFF_SC1);  float* sh1  = (float*)(wsb + OFF_SH1);
    float* sum2 = (float*)(wsb + OFF_SUM2); float* ssq2 = (float*)(wsb + OFF_SSQ2);
    float* sc2  = (float*)(wsb + OFF_SC2);  float* sh2  = (float*)(wsb + OFF_SH2);
    float* sum3 = (float*)(wsb + OFF_SUM3); float* ssq3 = (float*)(wsb + OFF_SSQ3);
    float* sc3  = (float*)(wsb + OFF_SC3);  float* sh3  = (float*)(wsb + OFF_SH3);

    hipMemsetAsync(wsb + OFF_TMAX, 0, STATS_END - OFF_TMAX, stream);

    absmax_k<<<74, 256, 0, stream>>>(w1, w2, wf1, wf2, tmax);
    quant_w1_k<<<4, 256, 0, stream>>>(w1, qw1, tmax);
    quant_w2c_k<<<200, 256, 0, stream>>>(w2, qw2c, tmax);
    quant_wf1c_k<<<2048, 256, 0, stream>>>(wf1, qwf1c, tmax);
    quant_wf2_k<<<20, 256, 0, stream>>>(wf2, qwf2, tmax);

    conv1_stats_k<<<768, 256, 0, stream>>>(x, qw1, sum1, ssq1);
    bn_fin_k<<<1, 256, 0, stream>>>(sum1, ssq1, g1, be1, sc1, sh1, 1.f / 2359296.f, 32);
    conv1_pool_k<<<2304, 256, 0, stream>>>(x, qw1, sc1, sh1, h1c);

    conv2_k<<<512, 256, 0, stream>>>(h1c, qw2c, y2c, sum2, ssq2);
    bn_fin_k<<<1, 256, 0, stream>>>(sum2, ssq2, g2, be2, sc2, sh2, 1.f / 262144.f, 64);
    pool2_k<<<16384, 256, 0, stream>>>(y2c, sc2, sh2, h2c);

    fc1_k<<<dim3(64, 8), 256, 0, stream>>>(h2c, qwf1c, y3);
    bn3_stats_k<<<512, 256, 0, stream>>>(y3, sum3, ssq3);
    bn_fin_k<<<2, 256, 0, stream>>>(sum3, ssq3, g3, be3, sc3, sh3, 1.f / 4096.f, 512);

    fc2_k<<<64, 256, 0, stream>>>(y3, sc3, sh3, qwf2, bf2, out);
}

// Round 7
// 306.865 us; speedup vs baseline: 8.0573x; 1.1237x over previous
//
#include <hip/hip_runtime.h>

#define TID ((int)threadIdx.x)
typedef unsigned short u16;
typedef short short8 __attribute__((ext_vector_type(8)));
typedef float f32x4 __attribute__((ext_vector_type(4)));

__device__ __forceinline__ u16 f2b(float f) {
    unsigned int x = __float_as_uint(f);
    return (u16)((x + 0x7fffu + ((x >> 16) & 1u)) >> 16);
}
__device__ __forceinline__ float b2f(u16 u) {
    return __uint_as_float(((unsigned int)u) << 16);
}

// ---------------- workspace layout (BYTE offsets) ----------------
static constexpr size_t OFF_QW1   = 0;         // 800 f32 [32][25]
static constexpr size_t OFF_QWF2  = 3200;      // 5120 f32 [10][512]
static constexpr size_t OFF_TMAX  = 23680;     // 4 uint
static constexpr size_t OFF_SUM1  = 23808, OFF_SSQ1 = 23936, OFF_SC1 = 24064, OFF_SH1 = 24192;
static constexpr size_t OFF_SUM2  = 24320, OFF_SSQ2 = 24576, OFF_SC2 = 24832, OFF_SH2 = 25088;
static constexpr size_t OFF_SUM3  = 25344, OFF_SSQ3 = 27392, OFF_SC3 = 29440, OFF_SH3 = 31488;
static constexpr size_t STATS_END = 33536;
static constexpr size_t OFF_QW2C  = 33792;     // bf16 [25 shift][64 oc][32 ic] = 102400 B
static constexpr size_t OFF_QWF1C = 136192;    // bf16 [512][1024] = 1048576 B
static constexpr size_t OFF_H1C   = 1184768;   // bf16 [4096][12][12][32] = 37748736 B
static constexpr size_t OFF_Y2C   = 38933504;  // bf16 [n][oc][64 pos] = 33554432 B
static constexpr size_t OFF_H2C   = 72487936;  // bf16 [4096][1024] = 8388608 B
static constexpr size_t OFF_Y3    = 80876544;  // f32 [512][4096] = 8388608 B
// total ~89.3 MB

// ---------------- abs-max of the 4 weight tensors ----------------
__global__ __launch_bounds__(256) void absmax_k(const float* w1, const float* w2,
                                                const float* wf1, const float* wf2,
                                                unsigned int* tmaxbits) {
    int bid = blockIdx.x;
    int b, lb, nb; const float* src; long n;
    if (bid < 1)       { b = 0; src = w1;  n = 800;    lb = bid;      nb = 1;  }
    else if (bid < 9)  { b = 1; src = w2;  n = 51200;  lb = bid - 1;  nb = 8;  }
    else if (bid < 73) { b = 2; src = wf1; n = 524288; lb = bid - 9;  nb = 64; }
    else               { b = 3; src = wf2; n = 5120;   lb = bid - 73; nb = 1;  }
    float m = 0.f;
    for (long i = (long)lb * 256 + TID; i < n; i += (long)nb * 256)
        m = fmaxf(m, fabsf(src[i]));
    __shared__ float red[256];
    red[TID] = m; __syncthreads();
    for (int s = 128; s > 0; s >>= 1) {
        if (TID < s) red[TID] = fmaxf(red[TID], red[TID + s]);
        __syncthreads();
    }
    if (TID == 0) atomicMax(&tmaxbits[b], __float_as_uint(red[0]));
}

// ---------------- all 4 quantizers in one launch ----------------
// w2 [oc][ic][5][5] -> qw2c bf16 [sh][oc][ic]; wf1 [512][1024] -> bf16 same layout
__global__ __launch_bounds__(256) void quant_all_k(const float* w1, const float* w2,
                                                   const float* wf1, const float* wf2,
                                                   float* qw1, u16* qw2c, u16* qwf1c,
                                                   float* qwf2, const unsigned int* tmax) {
    int bid = blockIdx.x;
    if (bid < 4) {
        int i = bid * 256 + TID; if (i >= 800) return;
        float t = 0.05f * __uint_as_float(tmax[0]);
        float v = w1[i];
        qw1[i] = (v > t) ? 1.f : ((v < -t) ? -1.f : 0.f);
    } else if (bid < 204) {
        int i = (bid - 4) * 256 + TID;       // < 51200
        float t = 0.05f * __uint_as_float(tmax[1]);
        int ic = i & 31, oc = (i >> 5) & 63, sh = i >> 11;
        float v = w2[(oc * 32 + ic) * 25 + sh];
        qw2c[i] = f2b((v > t) ? 1.f : ((v < -t) ? -1.f : 0.f));
    } else if (bid < 2252) {
        int i = (bid - 204) * 256 + TID;     // < 524288
        float t = 0.05f * __uint_as_float(tmax[2]);
        float v = wf1[i];
        qwf1c[i] = f2b((v > t) ? 1.f : ((v < -t) ? -1.f : 0.f));
    } else {
        int i = (bid - 2252) * 256 + TID;    // < 5120
        float t = 0.05f * __uint_as_float(tmax[3]);
        float v = wf2[i];
        qwf2[i] = (v > t) ? 1.f : ((v < -t) ? -1.f : 0.f);
    }
}

// ---------------- conv1 pass A: stats, ALL 32 channels per thread ----------------
// thread = (n, oy, half): 12 outputs from a 5x16 register patch; loop 32 channels.
__global__ __launch_bounds__(256) void conv1_stats_k(const float* __restrict__ x,
                                                     const float* __restrict__ qw1,
                                                     float* sum, float* ssq) {
    __shared__ float wl[800];
    __shared__ float psum[128], pssq[128];   // [4 waves][32 ch]
    for (int i = TID; i < 800; i += 256) wl[i] = qw1[i];
    __syncthreads();
    int p = blockIdx.x * 256 + TID;          // < 4096*48 exactly (grid.x = 768)
    int n = p / 48, rem = p % 48, oy = rem >> 1, half = rem & 1;
    int l = TID & 63, wv = TID >> 6;
    const float* xb = x + n * 784 + oy * 28 + half * 12;
    float rr[5][16];
    #pragma unroll
    for (int r = 0; r < 5; r++) {
        const float4* rp = reinterpret_cast<const float4*>(xb + r * 28);
        #pragma unroll
        for (int qq = 0; qq < 4; qq++) {
            float4 v = rp[qq];
            rr[r][qq * 4 + 0] = v.x; rr[r][qq * 4 + 1] = v.y;
            rr[r][qq * 4 + 2] = v.z; rr[r][qq * 4 + 3] = v.w;
        }
    }
    #pragma unroll 1
    for (int c = 0; c < 32; c++) {
        const float* wr = &wl[c * 25];
        float acc[12] = {};
        #pragma unroll
        for (int ky = 0; ky < 5; ky++)
            #pragma unroll
            for (int kx = 0; kx < 5; kx++) {
                float w = wr[ky * 5 + kx];
                #pragma unroll
                for (int ox = 0; ox < 12; ox++)
                    acc[ox] = fmaf(rr[ky][ox + kx], w, acc[ox]);
            }
        float sc = 0.f, s2c = 0.f;
        #pragma unroll
        for (int ox = 0; ox < 12; ox++) { sc += acc[ox]; s2c += acc[ox] * acc[ox]; }
        #pragma unroll
        for (int m = 1; m < 64; m <<= 1) {
            sc  += __shfl_xor(sc,  m);
            s2c += __shfl_xor(s2c, m);
        }
        if (l == 0) { psum[wv * 32 + c] = sc; pssq[wv * 32 + c] = s2c; }
    }
    __syncthreads();
    if (TID < 32) {
        float ts = psum[TID] + psum[32 + TID] + psum[64 + TID] + psum[96 + TID];
        float t2 = pssq[TID] + pssq[32 + TID] + pssq[64 + TID] + pssq[96 + TID];
        atomicAdd(&sum[TID], ts); atomicAdd(&ssq[TID], t2);
    }
}

// ---------------- BN finalize ----------------
__global__ void bn_fin_k(const float* sum, const float* ssq, const float* g,
                         const float* be, float* sc, float* sh, float inv_cnt, int C) {
    int c = blockIdx.x * 256 + TID;
    if (c >= C) return;
    float m = sum[c] * inv_cnt;
    float v = ssq[c] * inv_cnt - m * m;
    float s = g[c] / sqrtf(v + 1e-5f);
    sc[c] = s; sh[c] = be[c] - m * s;
}

// ---------------- conv1 pass B: thread = pooled pixel, ALL 32 ch fully unrolled ----------------
// #pragma unroll on c-loop keeps o[32] in VGPRs (round 6: it was LDS-lowered -> 4.9M bank conflicts)
__global__ __launch_bounds__(256) void conv1_pool_k(const float* __restrict__ x,
                                                    const float* __restrict__ qw1,
                                                    const float* sc, const float* sh,
                                                    u16* __restrict__ h1c) {
    __shared__ float wl[800];
    __shared__ float scs[32], shs[32];
    for (int i = TID; i < 800; i += 256) wl[i] = qw1[i];
    if (TID < 32) { scs[TID] = sc[TID]; shs[TID] = sh[TID]; }
    __syncthreads();
    int p = blockIdx.x * 256 + TID;          // < 4096*144 (grid.x = 2304)
    int n = p / 144, hw = p % 144;
    int py = hw / 12, px = hw % 12;
    const float* xb = x + n * 784 + (2 * py) * 28 + 2 * px;   // 8B-aligned
    float patch[6][6];
    #pragma unroll
    for (int r = 0; r < 6; r++) {
        const float2* rp = reinterpret_cast<const float2*>(xb + r * 28);
        #pragma unroll
        for (int cq = 0; cq < 3; cq++) {
            float2 v = rp[cq];
            patch[r][cq * 2] = v.x; patch[r][cq * 2 + 1] = v.y;
        }
    }
    u16 o[32];
    #pragma unroll
    for (int c = 0; c < 32; c++) {
        float a00 = 0.f, a01 = 0.f, a10 = 0.f, a11 = 0.f;
        const float* wr = &wl[c * 25];
        #pragma unroll
        for (int ky = 0; ky < 5; ky++)
            #pragma unroll
            for (int kx = 0; kx < 5; kx++) {
                float w = wr[ky * 5 + kx];
                a00 = fmaf(patch[ky][kx],     w, a00);
                a01 = fmaf(patch[ky][kx + 1], w, a01);
                a10 = fmaf(patch[ky + 1][kx],     w, a10);
                a11 = fmaf(patch[ky + 1][kx + 1], w, a11);
            }
        float scl = scs[c], shf = shs[c];
        float v = fmaxf(fmaxf(fmaxf(a00 * scl + shf, a01 * scl + shf),
                              fmaxf(a10 * scl + shf, a11 * scl + shf)), 0.f);
        o[c] = f2b(v);
    }
    float4* dst = reinterpret_cast<float4*>(h1c + (size_t)p * 32);
    const float4* ov = reinterpret_cast<const float4*>(o);
    #pragma unroll
    for (int qq = 0; qq < 4; qq++) dst[qq] = ov[qq];
}

// ---------------- conv2: MFMA implicit conv. block = 8 samples; wave = 16 ocs ----------------
// h1c: bf16 [n][12][12][32]; qw2c: bf16 [sh][oc][ic]; y2c: bf16 [n][oc][64 pos]
__global__ __launch_bounds__(256) void conv2_k(const u16* __restrict__ h1c,
                                               const u16* __restrict__ qw2c,
                                               u16* __restrict__ y2c,
                                               float* sum, float* ssq) {
    // LDS per sample: 12 rows * (12*64B + 16B pad) = 9408 B; 2 buffers
    __shared__ float4 hsm4[1176];            // 18816 B
    char* hsraw = (char*)hsm4;
    int n0 = blockIdx.x * 8;                 // grid.x = 512
    int l = TID & 63, wv = TID >> 6;
    int oc0 = wv * 16;
    int lm = l & 15, lr = (l >> 3) & 1, ox = l & 7, bq = l >> 4;
    // B fragments: 25 shifts, this wave's 16 ocs, held in VGPRs
    short8 bw[25];
    #pragma unroll
    for (int sh = 0; sh < 25; sh++)
        bw[sh] = *reinterpret_cast<const short8*>(qw2c + ((size_t)sh * 64 + oc0 + lm) * 32 + bq * 8);
    // per-lane LDS read bases per kx (swizzled channels-last)
    int xy[5];
    #pragma unroll
    for (int kx = 0; kx < 5; kx++) {
        int xx = ox + kx;
        xy[kx] = lr * 784 + xx * 64 + ((bq ^ (xx & 3)) * 16);
    }
    float sacc = 0.f, s2acc = 0.f;
    // stage sample 0
    {
        const float4* src = reinterpret_cast<const float4*>(h1c + (size_t)n0 * 4608);
        #pragma unroll
        for (int k = 0; k < 3; k++) {
            if (k < 2 || TID < 64) {
                int i = TID + k * 256;
                int pix = i >> 2, b = i & 3;
                int y = pix / 12, xx = pix - y * 12;
                *reinterpret_cast<float4*>(hsraw + y * 784 + xx * 64 + ((b ^ (xx & 3)) * 16)) = src[i];
            }
        }
    }
    #pragma unroll 1
    for (int s = 0; s < 8; s++) {
        __syncthreads();
        if (s < 7) {
            const float4* src = reinterpret_cast<const float4*>(h1c + (size_t)(n0 + s + 1) * 4608);
            char* dst = hsraw + ((s + 1) & 1) * 9408;
            #pragma unroll
            for (int k = 0; k < 3; k++) {
                if (k < 2 || TID < 64) {
                    int i = TID + k * 256;
                    int pix = i >> 2, b = i & 3;
                    int y = pix / 12, xx = pix - y * 12;
                    *reinterpret_cast<float4*>(dst + y * 784 + xx * 64 + ((b ^ (xx & 3)) * 16)) = src[i];
                }
            }
        }
        const char* hb = hsraw + (s & 1) * 9408;
        f32x4 acc[4] = {{0.f,0.f,0.f,0.f},{0.f,0.f,0.f,0.f},{0.f,0.f,0.f,0.f},{0.f,0.f,0.f,0.f}};
        #pragma unroll
        for (int ky = 0; ky < 5; ky++)
            #pragma unroll
            for (int kx = 0; kx < 5; kx++) {
                const int sh = ky * 5 + kx;
                #pragma unroll
                for (int mt = 0; mt < 4; mt++) {
                    short8 a = *reinterpret_cast<const short8*>(hb + xy[kx] + (mt * 2 + ky) * 784);
                    acc[mt] = __builtin_amdgcn_mfma_f32_16x16x32_bf16(a, bw[sh], acc[mt], 0, 0, 0);
                }
            }
        int n = n0 + s;
        #pragma unroll
        for (int mt = 0; mt < 4; mt++) {
            float v0 = acc[mt][0], v1 = acc[mt][1], v2 = acc[mt][2], v3 = acc[mt][3];
            sacc += v0 + v1 + v2 + v3;
            s2acc += v0 * v0 + v1 * v1 + v2 * v2 + v3 * v3;
            ushort4 u = make_ushort4(f2b(v0), f2b(v1), f2b(v2), f2b(v3));
            *reinterpret_cast<ushort4*>(y2c + (size_t)n * 4096 + (oc0 + lm) * 64 + mt * 16 + bq * 4) = u;
        }
    }
    // stats: lanes l, l^16, l^32, l^48 share oc = oc0+lm
    sacc  += __shfl_xor(sacc, 16);  sacc  += __shfl_xor(sacc, 32);
    s2acc += __shfl_xor(s2acc, 16); s2acc += __shfl_xor(s2acc, 32);
    if (l < 16) { atomicAdd(&sum[oc0 + l], sacc); atomicAdd(&ssq[oc0 + l], s2acc); }
}

// ---------------- pool2: BN + relu + maxpool; y2c bf16 [n][oc][64] -> h2c bf16 [n][1024] ----------------
__global__ __launch_bounds__(256) void pool2_k(const u16* __restrict__ y2c,
                                               const float* sc, const float* sh,
                                               u16* __restrict__ h2c) {
    int i = blockIdx.x * 256 + TID;          // < 4096*1024 (grid.x = 16384)
    int px = i & 3, py = (i >> 2) & 3, oc = (i >> 4) & 63, n = i >> 10;
    size_t base = (size_t)n * 4096 + oc * 64 + (2 * py) * 8 + 2 * px;
    float s = sc[oc], t = sh[oc];
    float a = b2f(y2c[base])     * s + t;
    float b = b2f(y2c[base + 1]) * s + t;
    float c = b2f(y2c[base + 8]) * s + t;
    float d = b2f(y2c[base + 9]) * s + t;
    float m = fmaxf(fmaxf(fmaxf(fmaxf(0.f, a), b), c), d);
    h2c[i] = f2b(m);                          // i == n*1024 + oc*16 + py*4 + px
}

// ---------------- fc1: MFMA GEMM [4096x1024]x[512x1024]^T -> y3T f32 [512][4096] ----------------
__global__ __launch_bounds__(256) void fc1_k(const u16* __restrict__ h2c,
                                             const u16* __restrict__ qwf1c,
                                             float* __restrict__ y3T) {
    __shared__ float4 Asm[576], Bsm[576];    // each 9216 B = 64 rows x 72 u16 (pad 8)
    u16* AsU = (u16*)Asm; u16* BsU = (u16*)Bsm;
    int m0 = blockIdx.x * 64, j0 = blockIdx.y * 64;
    int l = TID & 63, wv = TID >> 6;
    int lm = l & 15, q = l >> 4;
    int r0 = TID >> 3, c0 = TID & 7;
    f32x4 acc[4] = {{0.f,0.f,0.f,0.f},{0.f,0.f,0.f,0.f},{0.f,0.f,0.f,0.f},{0.f,0.f,0.f,0.f}};
    #pragma unroll 1
    for (int kc = 0; kc < 16; kc++) {
        int kk = kc * 64;
        if (kc) __syncthreads();
        #pragma unroll
        for (int i = 0; i < 2; i++) {
            int r = i * 32 + r0;
            *reinterpret_cast<float4*>(AsU + r * 72 + c0 * 8) =
                *reinterpret_cast<const float4*>(h2c + (size_t)(m0 + r) * 1024 + kk + c0 * 8);
            *reinterpret_cast<float4*>(BsU + r * 72 + c0 * 8) =
                *reinterpret_cast<const float4*>(qwf1c + (size_t)(j0 + r) * 1024 + kk + c0 * 8);
        }
        __syncthreads();
        #pragma unroll
        for (int half = 0; half < 2; half++) {
            short8 b = *reinterpret_cast<const short8*>(BsU + (wv * 16 + lm) * 72 + half * 32 + q * 8);
            #pragma unroll
            for (int mt = 0; mt < 4; mt++) {
                short8 a = *reinterpret_cast<const short8*>(AsU + (mt * 16 + lm) * 72 + half * 32 + q * 8);
                acc[mt] = __builtin_amdgcn_mfma_f32_16x16x32_bf16(a, b, acc[mt], 0, 0, 0);
            }
        }
    }
    #pragma unroll
    for (int mt = 0; mt < 4; mt++)
        *reinterpret_cast<f32x4*>(y3T + (size_t)(j0 + wv * 16 + lm) * 4096 + m0 + mt * 16 + q * 4) = acc[mt];
}

// ---------------- bn3 stats ----------------
__global__ __launch_bounds__(256) void bn3_stats_k(const float* __restrict__ y3T,
                                                   float* sum, float* ssq) {
    int j = blockIdx.x;
    __shared__ float r1[256], r2[256];
    float s = 0.f, s2 = 0.f;
    for (int n = TID; n < 4096; n += 256) {
        float v = y3T[(size_t)j * 4096 + n];
        s += v; s2 += v * v;
    }
    r1[TID] = s; r2[TID] = s2; __syncthreads();
    for (int st = 128; st > 0; st >>= 1) {
        if (TID < st) { r1[TID] += r1[TID + st]; r2[TID] += r2[TID + st]; }
        __syncthreads();
    }
    if (TID == 0) { sum[j] = r1[0]; ssq[j] = r2[0]; }
}

// ---------------- fc2: K-sliced; block = 64 n x 4 k-slices; grid.x = 64 ----------------
__global__ __launch_bounds__(256) void fc2_k(const float* __restrict__ y3T,
                                             const float* sc, const float* sh,
                                             const float* __restrict__ qwf2,
                                             const float* bf2, float* __restrict__ out) {
    __shared__ float wlds[5120];
    __shared__ float part[3][640];
    for (int i = TID; i < 5120; i += 256) wlds[i] = qwf2[i];
    __syncthreads();
    int nl = TID & 63, ks = TID >> 6;
    int n = blockIdx.x * 64 + nl;
    float acc[10] = {};
    for (int k = ks * 128; k < ks * 128 + 128; k++) {
        float v = fmaxf(y3T[(size_t)k * 4096 + n] * sc[k] + sh[k], 0.f);
        #pragma unroll
        for (int o = 0; o < 10; o++) acc[o] = fmaf(v, wlds[o * 512 + k], acc[o]);
    }
    if (ks > 0) {
        #pragma unroll
        for (int o = 0; o < 10; o++) part[ks - 1][o * 64 + nl] = acc[o];
    }
    __syncthreads();
    if (ks == 0) {
        #pragma unroll
        for (int o = 0; o < 10; o++)
            out[n * 10 + o] = acc[o] + part[0][o * 64 + nl] + part[1][o * 64 + nl]
                              + part[2][o * 64 + nl] + bf2[o];
    }
}

extern "C" void kernel_launch(void* const* d_in, const int* in_sizes, int n_in,
                              void* d_out, int out_size, void* d_ws, size_t ws_size,
                              hipStream_t stream) {
    char* wsb = (char*)d_ws;
    const float* x   = (const float*)d_in[0];
    const float* w1  = (const float*)d_in[1];
    // b1/b2/bf1 cancel under training-mode BN
    const float* g1  = (const float*)d_in[3];
    const float* be1 = (const float*)d_in[4];
    const float* w2  = (const float*)d_in[5];
    const float* g2  = (const float*)d_in[7];
    const float* be2 = (const float*)d_in[8];
    const float* wf1 = (const float*)d_in[9];
    const float* g3  = (const float*)d_in[11];
    const float* be3 = (const float*)d_in[12];
    const float* wf2 = (const float*)d_in[13];
    const float* bf2 = (const float*)d_in[14];
    float* out = (float*)d_out;

    unsigned int* tmax = (unsigned int*)(wsb + OFF_TMAX);
    float* qw1   = (float*)(wsb + OFF_QW1);
    float* qwf2  = (float*)(wsb + OFF_QWF2);
    u16*   qw2c  = (u16*)(wsb + OFF_QW2C);
    u16*   qwf1c = (u16*)(wsb + OFF_QWF1C);
    u16*   h1c   = (u16*)(wsb + OFF_H1C);
    u16*   y2c   = (u16*)(wsb + OFF_Y2C);
    u16*   h2c   = (u16*)(wsb + OFF_H2C);
    float* y3    = (float*)(wsb + OFF_Y3);

    float* sum1 = (float*)(wsb + OFF_SUM1); float* ssq1 = (float*)(wsb + OFF_SSQ1);
    float* sc1  = (float*)(wsb + OFF_SC1);  float* sh1  = (float*)(wsb + OFF_SH1);
    float* sum2 = (float*)(wsb + OFF_SUM2); float* ssq2 = (float*)(wsb + OFF_SSQ2);
    float* sc2  = (float*)(wsb + OFF_SC2);  float* sh2  = (float*)(wsb + OFF_SH2);
    float* sum3 = (float*)(wsb + OFF_SUM3); float* ssq3 = (float*)(wsb + OFF_SSQ3);
    float* sc3  = (float*)(wsb + OFF_SC3);  float* sh3  = (float*)(wsb + OFF_SH3);

    hipMemsetAsync(wsb + OFF_TMAX, 0, STATS_END - OFF_TMAX, stream);

    absmax_k<<<74, 256, 0, stream>>>(w1, w2, wf1, wf2, tmax);
    quant_all_k<<<2272, 256, 0, stream>>>(w1, w2, wf1, wf2, qw1, qw2c, qwf1c, qwf2, tmax);

    conv1_stats_k<<<768, 256, 0, stream>>>(x, qw1, sum1, ssq1);
    bn_fin_k<<<1, 256, 0, stream>>>(sum1, ssq1, g1, be1, sc1, sh1, 1.f / 2359296.f, 32);
    conv1_pool_k<<<2304, 256, 0, stream>>>(x, qw1, sc1, sh1, h1c);

    conv2_k<<<512, 256, 0, stream>>>(h1c, qw2c, y2c, sum2, ssq2);
    bn_fin_k<<<1, 256, 0, stream>>>(sum2, ssq2, g2, be2, sc2, sh2, 1.f / 262144.f, 64);
    pool2_k<<<16384, 256, 0, stream>>>(y2c, sc2, sh2, h2c);

    fc1_k<<<dim3(64, 8), 256, 0, stream>>>(h2c, qwf1c, y3);
    bn3_stats_k<<<512, 256, 0, stream>>>(y3, sum3, ssq3);
    bn_fin_k<<<2, 256, 0, stream>>>(sum3, ssq3, g3, be3, sc3, sh3, 1.f / 4096.f, 512);

    fc2_k<<<64, 256, 0, stream>>>(y3, sc3, sh3, qwf2, bf2, out);
}

// Round 8
// 284.522 us; speedup vs baseline: 8.6900x; 1.0785x over previous
//
#include <hip/hip_runtime.h>

#define TID ((int)threadIdx.x)
typedef unsigned short u16;
typedef short short8 __attribute__((ext_vector_type(8)));
typedef float f32x4 __attribute__((ext_vector_type(4)));

__device__ __forceinline__ u16 f2b(float f) {
    unsigned int x = __float_as_uint(f);
    return (u16)((x + 0x7fffu + ((x >> 16) & 1u)) >> 16);
}
__device__ __forceinline__ float b2f(u16 u) {
    return __uint_as_float(((unsigned int)u) << 16);
}

// ---------------- workspace layout (BYTE offsets) ----------------
static constexpr size_t OFF_QW1   = 0;         // 800 f32 [32][25]
static constexpr size_t OFF_QWF2  = 3200;      // 5120 f32 [10][512]
static constexpr size_t OFF_TMAX  = 23680;     // 4 uint
static constexpr size_t OFF_SUM1C = 23808;     // f32 [8 copies][32]
static constexpr size_t OFF_SSQ1C = 24832;     // f32 [8][32]
static constexpr size_t OFF_SUM2  = 25856, OFF_SSQ2 = 26112;   // f32 [64]
static constexpr size_t OFF_SUM3  = 26368, OFF_SSQ3 = 28416;   // f32 [512]
static constexpr size_t STATS_BEG = 23680, STATS_END = 30464;
static constexpr size_t OFF_QW2C  = 30720;     // bf16 [25 shift][64 oc][32 ic]
static constexpr size_t OFF_QWF1C = 133120;    // bf16 [512][1024]
static constexpr size_t OFF_Y1P   = 1181696;   // bf16 [4096][144][32]  PRE-BN pooled conv1
static constexpr size_t OFF_Y2C   = 38930432;  // bf16 [n][oc][64 pos]
static constexpr size_t OFF_H2C   = 72484864;  // bf16 [4096][1024]
static constexpr size_t OFF_Y3    = 80873472;  // f32 [512][4096]
// total ~89.3 MB

// ---------------- abs-max of the 4 weight tensors ----------------
__global__ __launch_bounds__(256) void absmax_k(const float* w1, const float* w2,
                                                const float* wf1, const float* wf2,
                                                unsigned int* tmaxbits) {
    int bid = blockIdx.x;
    int b, lb, nb; const float* src; long n;
    if (bid < 1)       { b = 0; src = w1;  n = 800;    lb = bid;      nb = 1;  }
    else if (bid < 9)  { b = 1; src = w2;  n = 51200;  lb = bid - 1;  nb = 8;  }
    else if (bid < 73) { b = 2; src = wf1; n = 524288; lb = bid - 9;  nb = 64; }
    else               { b = 3; src = wf2; n = 5120;   lb = bid - 73; nb = 1;  }
    float m = 0.f;
    for (long i = (long)lb * 256 + TID; i < n; i += (long)nb * 256)
        m = fmaxf(m, fabsf(src[i]));
    __shared__ float red[256];
    red[TID] = m; __syncthreads();
    for (int s = 128; s > 0; s >>= 1) {
        if (TID < s) red[TID] = fmaxf(red[TID], red[TID + s]);
        __syncthreads();
    }
    if (TID == 0) atomicMax(&tmaxbits[b], __float_as_uint(red[0]));
}

// ---------------- all 4 quantizers in one launch ----------------
__global__ __launch_bounds__(256) void quant_all_k(const float* w1, const float* w2,
                                                   const float* wf1, const float* wf2,
                                                   float* qw1, u16* qw2c, u16* qwf1c,
                                                   float* qwf2, const unsigned int* tmax) {
    int bid = blockIdx.x;
    if (bid < 4) {
        int i = bid * 256 + TID; if (i >= 800) return;
        float t = 0.05f * __uint_as_float(tmax[0]);
        float v = w1[i];
        qw1[i] = (v > t) ? 1.f : ((v < -t) ? -1.f : 0.f);
    } else if (bid < 204) {
        int i = (bid - 4) * 256 + TID;       // < 51200
        float t = 0.05f * __uint_as_float(tmax[1]);
        int ic = i & 31, oc = (i >> 5) & 63, sh = i >> 11;
        float v = w2[(oc * 32 + ic) * 25 + sh];
        qw2c[i] = f2b((v > t) ? 1.f : ((v < -t) ? -1.f : 0.f));
    } else if (bid < 2252) {
        int i = (bid - 204) * 256 + TID;     // < 524288
        float t = 0.05f * __uint_as_float(tmax[2]);
        float v = wf1[i];
        qwf1c[i] = f2b((v > t) ? 1.f : ((v < -t) ? -1.f : 0.f));
    } else {
        int i = (bid - 2252) * 256 + TID;    // < 5120
        float t = 0.05f * __uint_as_float(tmax[3]);
        float v = wf2[i];
        qwf2[i] = (v > t) ? 1.f : ((v < -t) ? -1.f : 0.f);
    }
}

// ---------------- conv1 fused: conv ONCE + stats + pre-BN maxpool ----------------
// Valid because relu(BN(x)) is monotone when BN scale>0 (g1=ones): maxpool commutes.
// thread = (n, pooled-row py, half, channel-pair cg): 2ch x 2 conv rows x 12 cols.
// Writes y1p bf16 NHWC [n][144][32] = maxpool2(conv1), PRE-BN.
__global__ __launch_bounds__(256) void conv1_fused_k(const float* __restrict__ x,
                                                     const float* __restrict__ qw1,
                                                     u16* __restrict__ y1p,
                                                     float* sum1c, float* ssq1c) {
    __shared__ float wl[800];
    __shared__ float red[4][64];
    for (int i = TID; i < 800; i += 256) wl[i] = qw1[i];
    __syncthreads();
    int p = blockIdx.x * 256 + TID;          // < 4096*384 (grid.x = 6144)
    int cg = p & 15, half = (p >> 4) & 1;
    int pr = p >> 5;                         // n*12 + py
    int py = pr % 12, n = pr / 12;
    int l = TID & 63, wv = TID >> 6;
    const float* xb = x + n * 784 + (2 * py) * 28 + half * 12;
    float patch[6][16];
    #pragma unroll
    for (int r = 0; r < 6; r++) {
        const float4* rp = reinterpret_cast<const float4*>(xb + r * 28);
        #pragma unroll
        for (int qq = 0; qq < 4; qq++) {
            float4 v = rp[qq];
            patch[r][qq * 4 + 0] = v.x; patch[r][qq * 4 + 1] = v.y;
            patch[r][qq * 4 + 2] = v.z; patch[r][qq * 4 + 3] = v.w;
        }
    }
    int c0 = cg * 2;
    float st[4];                              // s0, s1, q0, q1
    float pm[2][6];
    #pragma unroll 1
    for (int cc = 0; cc < 2; cc++) {
        const float* wr = &wl[(c0 + cc) * 25];
        float a0[12] = {}, a1[12] = {};
        #pragma unroll
        for (int ky = 0; ky < 5; ky++)
            #pragma unroll
            for (int kx = 0; kx < 5; kx++) {
                float w = wr[ky * 5 + kx];
                #pragma unroll
                for (int ox = 0; ox < 12; ox++) {
                    a0[ox] = fmaf(patch[ky][ox + kx], w, a0[ox]);
                    a1[ox] = fmaf(patch[ky + 1][ox + kx], w, a1[ox]);
                }
            }
        float s = 0.f, q = 0.f;
        #pragma unroll
        for (int ox = 0; ox < 12; ox++) {
            s += a0[ox] + a1[ox];
            q = fmaf(a0[ox], a0[ox], q); q = fmaf(a1[ox], a1[ox], q);
        }
        st[cc] = s; st[2 + cc] = q;
        #pragma unroll
        for (int j = 0; j < 6; j++)
            pm[cc][j] = fmaxf(fmaxf(a0[2 * j], a0[2 * j + 1]),
                              fmaxf(a1[2 * j], a1[2 * j + 1]));
    }
    // store: pixel P = py*12 + half*6 + j, channels c0, c0+1 (u32 pack)
    u16* base = y1p + (size_t)n * 4608 + (py * 12 + half * 6) * 32 + c0;
    #pragma unroll
    for (int j = 0; j < 6; j++) {
        unsigned int u = (unsigned int)f2b(pm[0][j]) | ((unsigned int)f2b(pm[1][j]) << 16);
        *reinterpret_cast<unsigned int*>(base + j * 32) = u;
    }
    // stats: lanes l, l^16, l^32, l^48 share cg
    #pragma unroll
    for (int t = 0; t < 4; t++) {
        st[t] += __shfl_xor(st[t], 16);
        st[t] += __shfl_xor(st[t], 32);
    }
    if (l < 16) {
        #pragma unroll
        for (int t = 0; t < 4; t++) red[wv][l * 4 + t] = st[t];
    }
    __syncthreads();
    if (TID < 64) {
        float v = red[0][TID] + red[1][TID] + red[2][TID] + red[3][TID];
        int t = TID & 3, ch = (TID >> 2) * 2 + (t & 1);
        float* dst = (t < 2 ? sum1c : ssq1c) + (blockIdx.x & 7) * 32 + ch;
        atomicAdd(dst, v);
    }
}

// ---------------- conv2: MFMA implicit conv; BN1+relu applied during LDS staging ----------------
// y1p: bf16 [n][144][32] pre-BN; qw2c: bf16 [sh][oc][ic]; y2c: bf16 [n][oc][64 pos]
__global__ __launch_bounds__(256) void conv2_k(const u16* __restrict__ y1p,
                                               const u16* __restrict__ qw2c,
                                               u16* __restrict__ y2c,
                                               const float* sum1c, const float* ssq1c,
                                               const float* g1, const float* be1,
                                               float* sum, float* ssq) {
    __shared__ float4 hsm4[1176];            // 2 x 9408 B
    __shared__ float scs[32], shs[32];
    char* hsraw = (char*)hsm4;
    int n0 = blockIdx.x * 8;                 // grid.x = 512
    int l = TID & 63, wv = TID >> 6;
    int oc0 = wv * 16;
    int lm = l & 15, lr = (l >> 3) & 1, ox = l & 7, bq = l >> 4;
    // BN1 finalize (per block, 32 ch)
    if (TID < 32) {
        float s = 0.f, q = 0.f;
        #pragma unroll
        for (int r = 0; r < 8; r++) { s += sum1c[r * 32 + TID]; q += ssq1c[r * 32 + TID]; }
        float m = s * (1.f / 2359296.f);
        float v = q * (1.f / 2359296.f) - m * m;
        float sc = g1[TID] / sqrtf(v + 1e-5f);
        scs[TID] = sc; shs[TID] = be1[TID] - m * sc;
    }
    __syncthreads();
    // per-thread BN regs for its staging channel group (b = TID&3 constant across iters)
    float scR[8], shR[8];
    {
        int b = TID & 3;
        #pragma unroll
        for (int j = 0; j < 8; j++) { scR[j] = scs[b * 8 + j]; shR[j] = shs[b * 8 + j]; }
    }
    short8 bw[25];
    #pragma unroll
    for (int sh = 0; sh < 25; sh++)
        bw[sh] = *reinterpret_cast<const short8*>(qw2c + ((size_t)sh * 64 + oc0 + lm) * 32 + bq * 8);
    int xy[5];
    #pragma unroll
    for (int kx = 0; kx < 5; kx++) {
        int xx = ox + kx;
        xy[kx] = lr * 784 + xx * 64 + ((bq ^ (xx & 3)) * 16);
    }
    float sacc = 0.f, s2acc = 0.f;
    // stage sample 0 (with BN+relu transform)
    {
        const uint4* src = reinterpret_cast<const uint4*>(y1p + (size_t)n0 * 4608);
        #pragma unroll
        for (int k = 0; k < 3; k++) {
            if (k < 2 || TID < 64) {
                int i = TID + k * 256;
                int pix = i >> 2, b = i & 3;
                int y = pix / 12, xx = pix - y * 12;
                union { uint4 v; u16 u[8]; } in, out;
                in.v = src[i];
                #pragma unroll
                for (int j = 0; j < 8; j++)
                    out.u[j] = f2b(fmaxf(fmaf(b2f(in.u[j]), scR[j], shR[j]), 0.f));
                *reinterpret_cast<uint4*>(hsraw + y * 784 + xx * 64 + ((b ^ (xx & 3)) * 16)) = out.v;
            }
        }
    }
    #pragma unroll 1
    for (int s = 0; s < 8; s++) {
        __syncthreads();
        if (s < 7) {
            const uint4* src = reinterpret_cast<const uint4*>(y1p + (size_t)(n0 + s + 1) * 4608);
            char* dst = hsraw + ((s + 1) & 1) * 9408;
            #pragma unroll
            for (int k = 0; k < 3; k++) {
                if (k < 2 || TID < 64) {
                    int i = TID + k * 256;
                    int pix = i >> 2, b = i & 3;
                    int y = pix / 12, xx = pix - y * 12;
                    union { uint4 v; u16 u[8]; } in, out;
                    in.v = src[i];
                    #pragma unroll
                    for (int j = 0; j < 8; j++)
                        out.u[j] = f2b(fmaxf(fmaf(b2f(in.u[j]), scR[j], shR[j]), 0.f));
                    *reinterpret_cast<uint4*>(dst + y * 784 + xx * 64 + ((b ^ (xx & 3)) * 16)) = out.v;
                }
            }
        }
        const char* hb = hsraw + (s & 1) * 9408;
        f32x4 acc[4] = {{0.f,0.f,0.f,0.f},{0.f,0.f,0.f,0.f},{0.f,0.f,0.f,0.f},{0.f,0.f,0.f,0.f}};
        #pragma unroll
        for (int ky = 0; ky < 5; ky++)
            #pragma unroll
            for (int kx = 0; kx < 5; kx++) {
                const int sh = ky * 5 + kx;
                #pragma unroll
                for (int mt = 0; mt < 4; mt++) {
                    short8 a = *reinterpret_cast<const short8*>(hb + xy[kx] + (mt * 2 + ky) * 784);
                    acc[mt] = __builtin_amdgcn_mfma_f32_16x16x32_bf16(a, bw[sh], acc[mt], 0, 0, 0);
                }
            }
        int n = n0 + s;
        #pragma unroll
        for (int mt = 0; mt < 4; mt++) {
            float v0 = acc[mt][0], v1 = acc[mt][1], v2 = acc[mt][2], v3 = acc[mt][3];
            sacc += v0 + v1 + v2 + v3;
            s2acc += v0 * v0 + v1 * v1 + v2 * v2 + v3 * v3;
            ushort4 u = make_ushort4(f2b(v0), f2b(v1), f2b(v2), f2b(v3));
            *reinterpret_cast<ushort4*>(y2c + (size_t)n * 4096 + (oc0 + lm) * 64 + mt * 16 + bq * 4) = u;
        }
    }
    sacc  += __shfl_xor(sacc, 16);  sacc  += __shfl_xor(sacc, 32);
    s2acc += __shfl_xor(s2acc, 16); s2acc += __shfl_xor(s2acc, 32);
    if (l < 16) { atomicAdd(&sum[oc0 + l], sacc); atomicAdd(&ssq[oc0 + l], s2acc); }
}

// ---------------- pool2: BN2 (inline finalize) + relu + maxpool ----------------
__global__ __launch_bounds__(256) void pool2_k(const u16* __restrict__ y2c,
                                               const float* sum2, const float* ssq2,
                                               const float* g2, const float* be2,
                                               u16* __restrict__ h2c) {
    int i = blockIdx.x * 256 + TID;          // < 4096*1024 (grid.x = 16384)
    int px = i & 3, py = (i >> 2) & 3, oc = (i >> 4) & 63, n = i >> 10;
    float m = sum2[oc] * (1.f / 262144.f);
    float v = ssq2[oc] * (1.f / 262144.f) - m * m;
    float s = g2[oc] / sqrtf(v + 1e-5f);
    float t = be2[oc] - m * s;
    size_t base = (size_t)n * 4096 + oc * 64 + (2 * py) * 8 + 2 * px;
    float a = b2f(y2c[base])     * s + t;
    float b = b2f(y2c[base + 1]) * s + t;
    float c = b2f(y2c[base + 8]) * s + t;
    float d = b2f(y2c[base + 9]) * s + t;
    float mm = fmaxf(fmaxf(fmaxf(fmaxf(0.f, a), b), c), d);
    h2c[i] = f2b(mm);
}

// ---------------- fc1: MFMA GEMM -> y3T f32 [512][4096]; bn3 stats in epilogue ----------------
__global__ __launch_bounds__(256) void fc1_k(const u16* __restrict__ h2c,
                                             const u16* __restrict__ qwf1c,
                                             float* __restrict__ y3T,
                                             float* sum3, float* ssq3) {
    __shared__ float4 Asm[576], Bsm[576];
    u16* AsU = (u16*)Asm; u16* BsU = (u16*)Bsm;
    int m0 = blockIdx.x * 64, j0 = blockIdx.y * 64;
    int l = TID & 63, wv = TID >> 6;
    int lm = l & 15, q = l >> 4;
    int r0 = TID >> 3, c0 = TID & 7;
    f32x4 acc[4] = {{0.f,0.f,0.f,0.f},{0.f,0.f,0.f,0.f},{0.f,0.f,0.f,0.f},{0.f,0.f,0.f,0.f}};
    #pragma unroll 1
    for (int kc = 0; kc < 16; kc++) {
        int kk = kc * 64;
        if (kc) __syncthreads();
        #pragma unroll
        for (int i = 0; i < 2; i++) {
            int r = i * 32 + r0;
            *reinterpret_cast<float4*>(AsU + r * 72 + c0 * 8) =
                *reinterpret_cast<const float4*>(h2c + (size_t)(m0 + r) * 1024 + kk + c0 * 8);
            *reinterpret_cast<float4*>(BsU + r * 72 + c0 * 8) =
                *reinterpret_cast<const float4*>(qwf1c + (size_t)(j0 + r) * 1024 + kk + c0 * 8);
        }
        __syncthreads();
        #pragma unroll
        for (int half = 0; half < 2; half++) {
            short8 b = *reinterpret_cast<const short8*>(BsU + (wv * 16 + lm) * 72 + half * 32 + q * 8);
            #pragma unroll
            for (int mt = 0; mt < 4; mt++) {
                short8 a = *reinterpret_cast<const short8*>(AsU + (mt * 16 + lm) * 72 + half * 32 + q * 8);
                acc[mt] = __builtin_amdgcn_mfma_f32_16x16x32_bf16(a, b, acc[mt], 0, 0, 0);
            }
        }
    }
    float s = 0.f, s2 = 0.f;
    #pragma unroll
    for (int mt = 0; mt < 4; mt++) {
        *reinterpret_cast<f32x4*>(y3T + (size_t)(j0 + wv * 16 + lm) * 4096 + m0 + mt * 16 + q * 4) = acc[mt];
        #pragma unroll
        for (int i = 0; i < 4; i++) { float v = acc[mt][i]; s += v; s2 = fmaf(v, v, s2); }
    }
    // all 16 values in this lane share j = j0 + wv*16 + lm; reduce over q (lanes ^16, ^32)
    s  += __shfl_xor(s, 16);  s  += __shfl_xor(s, 32);
    s2 += __shfl_xor(s2, 16); s2 += __shfl_xor(s2, 32);
    if (l < 16) {
        atomicAdd(&sum3[j0 + wv * 16 + l], s);
        atomicAdd(&ssq3[j0 + wv * 16 + l], s2);
    }
}

// ---------------- fc2: BN3 finalize inline (LDS) + relu + GEMV; grid.x = 64 ----------------
__global__ __launch_bounds__(256) void fc2_k(const float* __restrict__ y3T,
                                             const float* sum3, const float* ssq3,
                                             const float* g3, const float* be3,
                                             const float* __restrict__ qwf2,
                                             const float* bf2, float* __restrict__ out) {
    __shared__ float wlds[5120];
    __shared__ float part[3][640];
    __shared__ float sc3s[512], sh3s[512];
    for (int i = TID; i < 5120; i += 256) wlds[i] = qwf2[i];
    for (int k = TID; k < 512; k += 256) {
        float m = sum3[k] * (1.f / 4096.f);
        float v = ssq3[k] * (1.f / 4096.f) - m * m;
        float s = g3[k] / sqrtf(v + 1e-5f);
        sc3s[k] = s; sh3s[k] = be3[k] - m * s;
    }
    __syncthreads();
    int nl = TID & 63, ks = TID >> 6;
    int n = blockIdx.x * 64 + nl;
    float acc[10] = {};
    for (int k = ks * 128; k < ks * 128 + 128; k++) {
        float v = fmaxf(y3T[(size_t)k * 4096 + n] * sc3s[k] + sh3s[k], 0.f);
        #pragma unroll
        for (int o = 0; o < 10; o++) acc[o] = fmaf(v, wlds[o * 512 + k], acc[o]);
    }
    if (ks > 0) {
        #pragma unroll
        for (int o = 0; o < 10; o++) part[ks - 1][o * 64 + nl] = acc[o];
    }
    __syncthreads();
    if (ks == 0) {
        #pragma unroll
        for (int o = 0; o < 10; o++)
            out[n * 10 + o] = acc[o] + part[0][o * 64 + nl] + part[1][o * 64 + nl]
                              + part[2][o * 64 + nl] + bf2[o];
    }
}

extern "C" void kernel_launch(void* const* d_in, const int* in_sizes, int n_in,
                              void* d_out, int out_size, void* d_ws, size_t ws_size,
                              hipStream_t stream) {
    char* wsb = (char*)d_ws;
    const float* x   = (const float*)d_in[0];
    const float* w1  = (const float*)d_in[1];
    // b1/b2/bf1 cancel under training-mode BN
    const float* g1  = (const float*)d_in[3];
    const float* be1 = (const float*)d_in[4];
    const float* w2  = (const float*)d_in[5];
    const float* g2  = (const float*)d_in[7];
    const float* be2 = (const float*)d_in[8];
    const float* wf1 = (const float*)d_in[9];
    const float* g3  = (const float*)d_in[11];
    const float* be3 = (const float*)d_in[12];
    const float* wf2 = (const float*)d_in[13];
    const float* bf2 = (const float*)d_in[14];
    float* out = (float*)d_out;

    unsigned int* tmax = (unsigned int*)(wsb + OFF_TMAX);
    float* qw1   = (float*)(wsb + OFF_QW1);
    float* qwf2  = (float*)(wsb + OFF_QWF2);
    u16*   qw2c  = (u16*)(wsb + OFF_QW2C);
    u16*   qwf1c = (u16*)(wsb + OFF_QWF1C);
    u16*   y1p   = (u16*)(wsb + OFF_Y1P);
    u16*   y2c   = (u16*)(wsb + OFF_Y2C);
    u16*   h2c   = (u16*)(wsb + OFF_H2C);
    float* y3    = (float*)(wsb + OFF_Y3);

    float* sum1c = (float*)(wsb + OFF_SUM1C); float* ssq1c = (float*)(wsb + OFF_SSQ1C);
    float* sum2  = (float*)(wsb + OFF_SUM2);  float* ssq2  = (float*)(wsb + OFF_SSQ2);
    float* sum3  = (float*)(wsb + OFF_SUM3);  float* ssq3  = (float*)(wsb + OFF_SSQ3);

    hipMemsetAsync(wsb + STATS_BEG, 0, STATS_END - STATS_BEG, stream);

    absmax_k<<<74, 256, 0, stream>>>(w1, w2, wf1, wf2, tmax);
    quant_all_k<<<2272, 256, 0, stream>>>(w1, w2, wf1, wf2, qw1, qw2c, qwf1c, qwf2, tmax);

    conv1_fused_k<<<6144, 256, 0, stream>>>(x, qw1, y1p, sum1c, ssq1c);
    conv2_k<<<512, 256, 0, stream>>>(y1p, qw2c, y2c, sum1c, ssq1c, g1, be1, sum2, ssq2);
    pool2_k<<<16384, 256, 0, stream>>>(y2c, sum2, ssq2, g2, be2, h2c);
    fc1_k<<<dim3(64, 8), 256, 0, stream>>>(h2c, qwf1c, y3, sum3, ssq3);
    fc2_k<<<64, 256, 0, stream>>>(y3, sum3, ssq3, g3, be3, qwf2, bf2, out);
}

// Round 9
// 247.080 us; speedup vs baseline: 10.0069x; 1.1515x over previous
//
#include <hip/hip_runtime.h>

#define TID ((int)threadIdx.x)
typedef unsigned short u16;
typedef short short8 __attribute__((ext_vector_type(8)));
typedef float f32x4 __attribute__((ext_vector_type(4)));

__device__ __forceinline__ u16 f2b(float f) {
    unsigned int x = __float_as_uint(f);
    return (u16)((x + 0x7fffu + ((x >> 16) & 1u)) >> 16);
}
__device__ __forceinline__ float b2f(u16 u) {
    return __uint_as_float(((unsigned int)u) << 16);
}

// ---------------- workspace layout (BYTE offsets) ----------------
static constexpr size_t OFF_QW1   = 0;         // 800 f32 [32][25]
static constexpr size_t OFF_QWF2  = 3200;      // 5120 f32 [10][512]
static constexpr size_t OFF_TMAX  = 23680;     // 4 uint
static constexpr size_t OFF_SUM1C = 23808;     // f32 [8 copies][32]
static constexpr size_t OFF_SSQ1C = 24832;     // f32 [8][32]
static constexpr size_t OFF_SUM2  = 25856, OFF_SSQ2 = 26112;   // f32 [64]
static constexpr size_t OFF_SUM3  = 26368, OFF_SSQ3 = 28416;   // f32 [512]
static constexpr size_t STATS_BEG = 23680, STATS_END = 30464;
static constexpr size_t OFF_QW2C  = 30720;     // bf16 [25 shift][64 oc][32 ic]
static constexpr size_t OFF_QWF1C = 133120;    // bf16 [512][1024]
static constexpr size_t OFF_Y1P   = 1181696;   // bf16 [4096][144][32]  PRE-BN pooled conv1
static constexpr size_t OFF_Y2C   = 38930432;  // bf16 [n][oc][64 pos]
static constexpr size_t OFF_H2C   = 72484864;  // bf16 [4096][1024]
static constexpr size_t OFF_Y3    = 80873472;  // f32 [512][4096]
// total ~89.3 MB

// ---------------- abs-max of the 4 weight tensors ----------------
__global__ __launch_bounds__(256) void absmax_k(const float* w1, const float* w2,
                                                const float* wf1, const float* wf2,
                                                unsigned int* tmaxbits) {
    int bid = blockIdx.x;
    int b, lb, nb; const float* src; long n;
    if (bid < 1)       { b = 0; src = w1;  n = 800;    lb = bid;      nb = 1;  }
    else if (bid < 9)  { b = 1; src = w2;  n = 51200;  lb = bid - 1;  nb = 8;  }
    else if (bid < 73) { b = 2; src = wf1; n = 524288; lb = bid - 9;  nb = 64; }
    else               { b = 3; src = wf2; n = 5120;   lb = bid - 73; nb = 1;  }
    float m = 0.f;
    for (long i = (long)lb * 256 + TID; i < n; i += (long)nb * 256)
        m = fmaxf(m, fabsf(src[i]));
    __shared__ float red[256];
    red[TID] = m; __syncthreads();
    for (int s = 128; s > 0; s >>= 1) {
        if (TID < s) red[TID] = fmaxf(red[TID], red[TID + s]);
        __syncthreads();
    }
    if (TID == 0) atomicMax(&tmaxbits[b], __float_as_uint(red[0]));
}

// ---------------- all 4 quantizers in one launch ----------------
__global__ __launch_bounds__(256) void quant_all_k(const float* w1, const float* w2,
                                                   const float* wf1, const float* wf2,
                                                   float* qw1, u16* qw2c, u16* qwf1c,
                                                   float* qwf2, const unsigned int* tmax) {
    int bid = blockIdx.x;
    if (bid < 4) {
        int i = bid * 256 + TID; if (i >= 800) return;
        float t = 0.05f * __uint_as_float(tmax[0]);
        float v = w1[i];
        qw1[i] = (v > t) ? 1.f : ((v < -t) ? -1.f : 0.f);
    } else if (bid < 204) {
        int i = (bid - 4) * 256 + TID;       // < 51200
        float t = 0.05f * __uint_as_float(tmax[1]);
        int ic = i & 31, oc = (i >> 5) & 63, sh = i >> 11;
        float v = w2[(oc * 32 + ic) * 25 + sh];
        qw2c[i] = f2b((v > t) ? 1.f : ((v < -t) ? -1.f : 0.f));
    } else if (bid < 2252) {
        int i = (bid - 204) * 256 + TID;     // < 524288
        float t = 0.05f * __uint_as_float(tmax[2]);
        float v = wf1[i];
        qwf1c[i] = f2b((v > t) ? 1.f : ((v < -t) ? -1.f : 0.f));
    } else {
        int i = (bid - 2252) * 256 + TID;    // < 5120
        float t = 0.05f * __uint_as_float(tmax[3]);
        float v = wf2[i];
        qwf2[i] = (v > t) ? 1.f : ((v < -t) ? -1.f : 0.f);
    }
}

// ---------------- conv1 fused: conv ONCE + stats + pre-BN maxpool ----------------
// relu(BN(x)) monotone (g1=ones>0) => maxpool commutes => pool pre-BN values.
// thread = (n, py, half, channel-pair): 2ch x 2 conv rows x 12 cols.
// Channel loop FULLY UNROLLED: round-8's #pragma unroll 1 made pm[cc][..]
// dynamically indexed -> LDS-lowered scratch (16.9KB/block, 590K conflicts).
__global__ __launch_bounds__(256) void conv1_fused_k(const float* __restrict__ x,
                                                     const float* __restrict__ qw1,
                                                     u16* __restrict__ y1p,
                                                     float* sum1c, float* ssq1c) {
    __shared__ float wl[800];
    __shared__ float red[4][64];
    for (int i = TID; i < 800; i += 256) wl[i] = qw1[i];
    __syncthreads();
    int p = blockIdx.x * 256 + TID;          // < 4096*384 (grid.x = 6144)
    int cg = p & 15, half = (p >> 4) & 1;
    int pr = p >> 5;                         // n*12 + py
    int py = pr % 12, n = pr / 12;
    int l = TID & 63, wv = TID >> 6;
    const float* xb = x + n * 784 + (2 * py) * 28 + half * 12;
    float patch[6][16];
    #pragma unroll
    for (int r = 0; r < 6; r++) {
        const float4* rp = reinterpret_cast<const float4*>(xb + r * 28);
        #pragma unroll
        for (int qq = 0; qq < 4; qq++) {
            float4 v = rp[qq];
            patch[r][qq * 4 + 0] = v.x; patch[r][qq * 4 + 1] = v.y;
            patch[r][qq * 4 + 2] = v.z; patch[r][qq * 4 + 3] = v.w;
        }
    }
    int c0 = cg * 2;
    float st[4];                              // s0, s1, q0, q1
    float pm[2][6];
    #pragma unroll
    for (int cc = 0; cc < 2; cc++) {
        const float* wr = &wl[(c0 + cc) * 25];
        float a0[12] = {}, a1[12] = {};
        #pragma unroll
        for (int ky = 0; ky < 5; ky++)
            #pragma unroll
            for (int kx = 0; kx < 5; kx++) {
                float w = wr[ky * 5 + kx];
                #pragma unroll
                for (int ox = 0; ox < 12; ox++) {
                    a0[ox] = fmaf(patch[ky][ox + kx], w, a0[ox]);
                    a1[ox] = fmaf(patch[ky + 1][ox + kx], w, a1[ox]);
                }
            }
        float s = 0.f, q = 0.f;
        #pragma unroll
        for (int ox = 0; ox < 12; ox++) {
            s += a0[ox] + a1[ox];
            q = fmaf(a0[ox], a0[ox], q); q = fmaf(a1[ox], a1[ox], q);
        }
        st[cc] = s; st[2 + cc] = q;
        #pragma unroll
        for (int j = 0; j < 6; j++)
            pm[cc][j] = fmaxf(fmaxf(a0[2 * j], a0[2 * j + 1]),
                              fmaxf(a1[2 * j], a1[2 * j + 1]));
    }
    // store: pixel P = py*12 + half*6 + j, channels c0, c0+1 (u32 pack)
    u16* base = y1p + (size_t)n * 4608 + (py * 12 + half * 6) * 32 + c0;
    #pragma unroll
    for (int j = 0; j < 6; j++) {
        unsigned int u = (unsigned int)f2b(pm[0][j]) | ((unsigned int)f2b(pm[1][j]) << 16);
        *reinterpret_cast<unsigned int*>(base + j * 32) = u;
    }
    // stats: lanes l, l^16, l^32, l^48 share cg
    #pragma unroll
    for (int t = 0; t < 4; t++) {
        st[t] += __shfl_xor(st[t], 16);
        st[t] += __shfl_xor(st[t], 32);
    }
    if (l < 16) {
        #pragma unroll
        for (int t = 0; t < 4; t++) red[wv][l * 4 + t] = st[t];
    }
    __syncthreads();
    if (TID < 64) {
        float v = red[0][TID] + red[1][TID] + red[2][TID] + red[3][TID];
        int t = TID & 3, ch = (TID >> 2) * 2 + (t & 1);
        float* dst = (t < 2 ? sum1c : ssq1c) + (blockIdx.x & 7) * 32 + ch;
        atomicAdd(dst, v);
    }
}

// ---------------- conv2: MFMA implicit conv; BN1+relu applied during LDS staging ----------------
// y1p: bf16 [n][144][32] pre-BN; qw2c: bf16 [sh][oc][ic]; y2c: bf16 [n][oc][64 pos]
__global__ __launch_bounds__(256) void conv2_k(const u16* __restrict__ y1p,
                                               const u16* __restrict__ qw2c,
                                               u16* __restrict__ y2c,
                                               const float* sum1c, const float* ssq1c,
                                               const float* g1, const float* be1,
                                               float* sum, float* ssq) {
    __shared__ float4 hsm4[1176];            // 2 x 9408 B
    __shared__ float scs[32], shs[32];
    char* hsraw = (char*)hsm4;
    int n0 = blockIdx.x * 8;                 // grid.x = 512
    int l = TID & 63, wv = TID >> 6;
    int oc0 = wv * 16;
    int lm = l & 15, lr = (l >> 3) & 1, ox = l & 7, bq = l >> 4;
    // BN1 finalize (per block, 32 ch)
    if (TID < 32) {
        float s = 0.f, q = 0.f;
        #pragma unroll
        for (int r = 0; r < 8; r++) { s += sum1c[r * 32 + TID]; q += ssq1c[r * 32 + TID]; }
        float m = s * (1.f / 2359296.f);
        float v = q * (1.f / 2359296.f) - m * m;
        float sc = g1[TID] / sqrtf(v + 1e-5f);
        scs[TID] = sc; shs[TID] = be1[TID] - m * sc;
    }
    __syncthreads();
    float scR[8], shR[8];
    {
        int b = TID & 3;
        #pragma unroll
        for (int j = 0; j < 8; j++) { scR[j] = scs[b * 8 + j]; shR[j] = shs[b * 8 + j]; }
    }
    short8 bw[25];
    #pragma unroll
    for (int sh = 0; sh < 25; sh++)
        bw[sh] = *reinterpret_cast<const short8*>(qw2c + ((size_t)sh * 64 + oc0 + lm) * 32 + bq * 8);
    int xy[5];
    #pragma unroll
    for (int kx = 0; kx < 5; kx++) {
        int xx = ox + kx;
        xy[kx] = lr * 784 + xx * 64 + ((bq ^ (xx & 3)) * 16);
    }
    float sacc = 0.f, s2acc = 0.f;
    // stage sample 0 (with BN+relu transform)
    {
        const uint4* src = reinterpret_cast<const uint4*>(y1p + (size_t)n0 * 4608);
        #pragma unroll
        for (int k = 0; k < 3; k++) {
            if (k < 2 || TID < 64) {
                int i = TID + k * 256;
                int pix = i >> 2, b = i & 3;
                int y = pix / 12, xx = pix - y * 12;
                union { uint4 v; u16 u[8]; } in, out;
                in.v = src[i];
                #pragma unroll
                for (int j = 0; j < 8; j++)
                    out.u[j] = f2b(fmaxf(fmaf(b2f(in.u[j]), scR[j], shR[j]), 0.f));
                *reinterpret_cast<uint4*>(hsraw + y * 784 + xx * 64 + ((b ^ (xx & 3)) * 16)) = out.v;
            }
        }
    }
    #pragma unroll 1
    for (int s = 0; s < 8; s++) {
        __syncthreads();
        if (s < 7) {
            const uint4* src = reinterpret_cast<const uint4*>(y1p + (size_t)(n0 + s + 1) * 4608);
            char* dst = hsraw + ((s + 1) & 1) * 9408;
            #pragma unroll
            for (int k = 0; k < 3; k++) {
                if (k < 2 || TID < 64) {
                    int i = TID + k * 256;
                    int pix = i >> 2, b = i & 3;
                    int y = pix / 12, xx = pix - y * 12;
                    union { uint4 v; u16 u[8]; } in, out;
                    in.v = src[i];
                    #pragma unroll
                    for (int j = 0; j < 8; j++)
                        out.u[j] = f2b(fmaxf(fmaf(b2f(in.u[j]), scR[j], shR[j]), 0.f));
                    *reinterpret_cast<uint4*>(dst + y * 784 + xx * 64 + ((b ^ (xx & 3)) * 16)) = out.v;
                }
            }
        }
        const char* hb = hsraw + (s & 1) * 9408;
        f32x4 acc[4] = {{0.f,0.f,0.f,0.f},{0.f,0.f,0.f,0.f},{0.f,0.f,0.f,0.f},{0.f,0.f,0.f,0.f}};
        #pragma unroll
        for (int ky = 0; ky < 5; ky++)
            #pragma unroll
            for (int kx = 0; kx < 5; kx++) {
                const int sh = ky * 5 + kx;
                #pragma unroll
                for (int mt = 0; mt < 4; mt++) {
                    short8 a = *reinterpret_cast<const short8*>(hb + xy[kx] + (mt * 2 + ky) * 784);
                    acc[mt] = __builtin_amdgcn_mfma_f32_16x16x32_bf16(a, bw[sh], acc[mt], 0, 0, 0);
                }
            }
        int n = n0 + s;
        #pragma unroll
        for (int mt = 0; mt < 4; mt++) {
            float v0 = acc[mt][0], v1 = acc[mt][1], v2 = acc[mt][2], v3 = acc[mt][3];
            sacc += v0 + v1 + v2 + v3;
            s2acc += v0 * v0 + v1 * v1 + v2 * v2 + v3 * v3;
            ushort4 u = make_ushort4(f2b(v0), f2b(v1), f2b(v2), f2b(v3));
            *reinterpret_cast<ushort4*>(y2c + (size_t)n * 4096 + (oc0 + lm) * 64 + mt * 16 + bq * 4) = u;
        }
    }
    sacc  += __shfl_xor(sacc, 16);  sacc  += __shfl_xor(sacc, 32);
    s2acc += __shfl_xor(s2acc, 16); s2acc += __shfl_xor(s2acc, 32);
    if (l < 16) { atomicAdd(&sum[oc0 + l], sacc); atomicAdd(&ssq[oc0 + l], s2acc); }
}

// ---------------- pool2: BN2 (inline finalize) + relu + maxpool ----------------
__global__ __launch_bounds__(256) void pool2_k(const u16* __restrict__ y2c,
                                               const float* sum2, const float* ssq2,
                                               const float* g2, const float* be2,
                                               u16* __restrict__ h2c) {
    int i = blockIdx.x * 256 + TID;          // < 4096*1024 (grid.x = 16384)
    int px = i & 3, py = (i >> 2) & 3, oc = (i >> 4) & 63, n = i >> 10;
    float m = sum2[oc] * (1.f / 262144.f);
    float v = ssq2[oc] * (1.f / 262144.f) - m * m;
    float s = g2[oc] / sqrtf(v + 1e-5f);
    float t = be2[oc] - m * s;
    size_t base = (size_t)n * 4096 + oc * 64 + (2 * py) * 8 + 2 * px;
    float a = b2f(y2c[base])     * s + t;
    float b = b2f(y2c[base + 1]) * s + t;
    float c = b2f(y2c[base + 8]) * s + t;
    float d = b2f(y2c[base + 9]) * s + t;
    float mm = fmaxf(fmaxf(fmaxf(fmaxf(0.f, a), b), c), d);
    h2c[i] = f2b(mm);
}

// ---------------- fc1: MFMA GEMM -> y3T f32 [512][4096]; bn3 stats in epilogue ----------------
__global__ __launch_bounds__(256) void fc1_k(const u16* __restrict__ h2c,
                                             const u16* __restrict__ qwf1c,
                                             float* __restrict__ y3T,
                                             float* sum3, float* ssq3) {
    __shared__ float4 Asm[576], Bsm[576];
    u16* AsU = (u16*)Asm; u16* BsU = (u16*)Bsm;
    int m0 = blockIdx.x * 64, j0 = blockIdx.y * 64;
    int l = TID & 63, wv = TID >> 6;
    int lm = l & 15, q = l >> 4;
    int r0 = TID >> 3, c0 = TID & 7;
    f32x4 acc[4] = {{0.f,0.f,0.f,0.f},{0.f,0.f,0.f,0.f},{0.f,0.f,0.f,0.f},{0.f,0.f,0.f,0.f}};
    #pragma unroll 1
    for (int kc = 0; kc < 16; kc++) {
        int kk = kc * 64;
        if (kc) __syncthreads();
        #pragma unroll
        for (int i = 0; i < 2; i++) {
            int r = i * 32 + r0;
            *reinterpret_cast<float4*>(AsU + r * 72 + c0 * 8) =
                *reinterpret_cast<const float4*>(h2c + (size_t)(m0 + r) * 1024 + kk + c0 * 8);
            *reinterpret_cast<float4*>(BsU + r * 72 + c0 * 8) =
                *reinterpret_cast<const float4*>(qwf1c + (size_t)(j0 + r) * 1024 + kk + c0 * 8);
        }
        __syncthreads();
        #pragma unroll
        for (int half = 0; half < 2; half++) {
            short8 b = *reinterpret_cast<const short8*>(BsU + (wv * 16 + lm) * 72 + half * 32 + q * 8);
            #pragma unroll
            for (int mt = 0; mt < 4; mt++) {
                short8 a = *reinterpret_cast<const short8*>(AsU + (mt * 16 + lm) * 72 + half * 32 + q * 8);
                acc[mt] = __builtin_amdgcn_mfma_f32_16x16x32_bf16(a, b, acc[mt], 0, 0, 0);
            }
        }
    }
    float s = 0.f, s2 = 0.f;
    #pragma unroll
    for (int mt = 0; mt < 4; mt++) {
        *reinterpret_cast<f32x4*>(y3T + (size_t)(j0 + wv * 16 + lm) * 4096 + m0 + mt * 16 + q * 4) = acc[mt];
        #pragma unroll
        for (int i = 0; i < 4; i++) { float v = acc[mt][i]; s += v; s2 = fmaf(v, v, s2); }
    }
    s  += __shfl_xor(s, 16);  s  += __shfl_xor(s, 32);
    s2 += __shfl_xor(s2, 16); s2 += __shfl_xor(s2, 32);
    if (l < 16) {
        atomicAdd(&sum3[j0 + wv * 16 + l], s);
        atomicAdd(&ssq3[j0 + wv * 16 + l], s2);
    }
}

// ---------------- fc2: BN3 finalize inline (LDS) + relu + GEMV; grid.x = 64 ----------------
__global__ __launch_bounds__(256) void fc2_k(const float* __restrict__ y3T,
                                             const float* sum3, const float* ssq3,
                                             const float* g3, const float* be3,
                                             const float* __restrict__ qwf2,
                                             const float* bf2, float* __restrict__ out) {
    __shared__ float wlds[5120];
    __shared__ float part[3][640];
    __shared__ float sc3s[512], sh3s[512];
    for (int i = TID; i < 5120; i += 256) wlds[i] = qwf2[i];
    for (int k = TID; k < 512; k += 256) {
        float m = sum3[k] * (1.f / 4096.f);
        float v = ssq3[k] * (1.f / 4096.f) - m * m;
        float s = g3[k] / sqrtf(v + 1e-5f);
        sc3s[k] = s; sh3s[k] = be3[k] - m * s;
    }
    __syncthreads();
    int nl = TID & 63, ks = TID >> 6;
    int n = blockIdx.x * 64 + nl;
    float acc[10] = {};
    for (int k = ks * 128; k < ks * 128 + 128; k++) {
        float v = fmaxf(y3T[(size_t)k * 4096 + n] * sc3s[k] + sh3s[k], 0.f);
        #pragma unroll
        for (int o = 0; o < 10; o++) acc[o] = fmaf(v, wlds[o * 512 + k], acc[o]);
    }
    if (ks > 0) {
        #pragma unroll
        for (int o = 0; o < 10; o++) part[ks - 1][o * 64 + nl] = acc[o];
    }
    __syncthreads();
    if (ks == 0) {
        #pragma unroll
        for (int o = 0; o < 10; o++)
            out[n * 10 + o] = acc[o] + part[0][o * 64 + nl] + part[1][o * 64 + nl]
                              + part[2][o * 64 + nl] + bf2[o];
    }
}

extern "C" void kernel_launch(void* const* d_in, const int* in_sizes, int n_in,
                              void* d_out, int out_size, void* d_ws, size_t ws_size,
                              hipStream_t stream) {
    char* wsb = (char*)d_ws;
    const float* x   = (const float*)d_in[0];
    const float* w1  = (const float*)d_in[1];
    // b1/b2/bf1 cancel under training-mode BN
    const float* g1  = (const float*)d_in[3];
    const float* be1 = (const float*)d_in[4];
    const float* w2  = (const float*)d_in[5];
    const float* g2  = (const float*)d_in[7];
    const float* be2 = (const float*)d_in[8];
    const float* wf1 = (const float*)d_in[9];
    const float* g3  = (const float*)d_in[11];
    const float* be3 = (const float*)d_in[12];
    const float* wf2 = (const float*)d_in[13];
    const float* bf2 = (const float*)d_in[14];
    float* out = (float*)d_out;

    unsigned int* tmax = (unsigned int*)(wsb + OFF_TMAX);
    float* qw1   = (float*)(wsb + OFF_QW1);
    float* qwf2  = (float*)(wsb + OFF_QWF2);
    u16*   qw2c  = (u16*)(wsb + OFF_QW2C);
    u16*   qwf1c = (u16*)(wsb + OFF_QWF1C);
    u16*   y1p   = (u16*)(wsb + OFF_Y1P);
    u16*   y2c   = (u16*)(wsb + OFF_Y2C);
    u16*   h2c   = (u16*)(wsb + OFF_H2C);
    float* y3    = (float*)(wsb + OFF_Y3);

    float* sum1c = (float*)(wsb + OFF_SUM1C); float* ssq1c = (float*)(wsb + OFF_SSQ1C);
    float* sum2  = (float*)(wsb + OFF_SUM2);  float* ssq2  = (float*)(wsb + OFF_SSQ2);
    float* sum3  = (float*)(wsb + OFF_SUM3);  float* ssq3  = (float*)(wsb + OFF_SSQ3);

    hipMemsetAsync(wsb + STATS_BEG, 0, STATS_END - STATS_BEG, stream);

    absmax_k<<<74, 256, 0, stream>>>(w1, w2, wf1, wf2, tmax);
    quant_all_k<<<2272, 256, 0, stream>>>(w1, w2, wf1, wf2, qw1, qw2c, qwf1c, qwf2, tmax);

    conv1_fused_k<<<6144, 256, 0, stream>>>(x, qw1, y1p, sum1c, ssq1c);
    conv2_k<<<512, 256, 0, stream>>>(y1p, qw2c, y2c, sum1c, ssq1c, g1, be1, sum2, ssq2);
    pool2_k<<<16384, 256, 0, stream>>>(y2c, sum2, ssq2, g2, be2, h2c);
    fc1_k<<<dim3(64, 8), 256, 0, stream>>>(h2c, qwf1c, y3, sum3, ssq3);
    fc2_k<<<64, 256, 0, stream>>>(y3, sum3, ssq3, g3, be3, qwf2, bf2, out);
}

// Round 10
// 235.046 us; speedup vs baseline: 10.5193x; 1.0512x over previous
//
#include <hip/hip_runtime.h>

#define TID ((int)threadIdx.x)
typedef unsigned short u16;
typedef short short8 __attribute__((ext_vector_type(8)));
typedef float f32x4 __attribute__((ext_vector_type(4)));

__device__ __forceinline__ u16 f2b(float f) {
    unsigned int x = __float_as_uint(f);
    return (u16)((x + 0x7fffu + ((x >> 16) & 1u)) >> 16);
}
__device__ __forceinline__ float b2f(u16 u) {
    return __uint_as_float(((unsigned int)u) << 16);
}

// ---------------- workspace layout (BYTE offsets) ----------------
static constexpr size_t OFF_QW1   = 0;         // 800 f32 [32][25]
static constexpr size_t OFF_QWF2  = 3200;      // 5120 f32 [10][512]
static constexpr size_t OFF_TMAX  = 23680;     // 4 uint
static constexpr size_t OFF_SUM1C = 23808;     // f32 [8 copies][32]
static constexpr size_t OFF_SSQ1C = 24832;     // f32 [8][32]
static constexpr size_t OFF_SUM2  = 25856, OFF_SSQ2 = 26112;   // f32 [64]
static constexpr size_t OFF_SUM3  = 26368, OFF_SSQ3 = 28416;   // f32 [512]
static constexpr size_t STATS_BEG = 23680, STATS_END = 30464;
static constexpr size_t OFF_QW2C  = 30720;     // bf16 [25 shift][64 oc][32 ic]
static constexpr size_t OFF_QWF1C = 133120;    // bf16 [512][1024]
static constexpr size_t OFF_Y1P   = 1181696;   // bf16 [4096][144][32]  PRE-BN pooled conv1
static constexpr size_t OFF_Y2C   = 38930432;  // bf16 [n][oc][64 pos]
static constexpr size_t OFF_H2C   = 72484864;  // bf16 [4096][1024]
static constexpr size_t OFF_Y3    = 80873472;  // f32 [512][4096]
// total ~89.3 MB

// ---------------- abs-max of the 4 weight tensors ----------------
__global__ __launch_bounds__(256) void absmax_k(const float* w1, const float* w2,
                                                const float* wf1, const float* wf2,
                                                unsigned int* tmaxbits) {
    int bid = blockIdx.x;
    int b, lb, nb; const float* src; long n;
    if (bid < 1)        { b = 0; src = w1;  n = 800;    lb = bid;       nb = 1;   }
    else if (bid < 9)   { b = 1; src = w2;  n = 51200;  lb = bid - 1;   nb = 8;   }
    else if (bid < 265) { b = 2; src = wf1; n = 524288; lb = bid - 9;   nb = 256; }
    else                { b = 3; src = wf2; n = 5120;   lb = bid - 265; nb = 1;   }
    float m = 0.f;
    for (long i = (long)lb * 256 + TID; i < n; i += (long)nb * 256)
        m = fmaxf(m, fabsf(src[i]));
    __shared__ float red[256];
    red[TID] = m; __syncthreads();
    for (int s = 128; s > 0; s >>= 1) {
        if (TID < s) red[TID] = fmaxf(red[TID], red[TID + s]);
        __syncthreads();
    }
    if (TID == 0) atomicMax(&tmaxbits[b], __float_as_uint(red[0]));
}

// ---------------- all 4 quantizers in one launch ----------------
__global__ __launch_bounds__(256) void quant_all_k(const float* w1, const float* w2,
                                                   const float* wf1, const float* wf2,
                                                   float* qw1, u16* qw2c, u16* qwf1c,
                                                   float* qwf2, const unsigned int* tmax) {
    int bid = blockIdx.x;
    if (bid < 4) {
        int i = bid * 256 + TID; if (i >= 800) return;
        float t = 0.05f * __uint_as_float(tmax[0]);
        float v = w1[i];
        qw1[i] = (v > t) ? 1.f : ((v < -t) ? -1.f : 0.f);
    } else if (bid < 204) {
        int i = (bid - 4) * 256 + TID;       // < 51200
        float t = 0.05f * __uint_as_float(tmax[1]);
        int ic = i & 31, oc = (i >> 5) & 63, sh = i >> 11;
        float v = w2[(oc * 32 + ic) * 25 + sh];
        qw2c[i] = f2b((v > t) ? 1.f : ((v < -t) ? -1.f : 0.f));
    } else if (bid < 2252) {
        int i = (bid - 204) * 256 + TID;     // < 524288
        float t = 0.05f * __uint_as_float(tmax[2]);
        float v = wf1[i];
        qwf1c[i] = f2b((v > t) ? 1.f : ((v < -t) ? -1.f : 0.f));
    } else {
        int i = (bid - 2252) * 256 + TID;    // < 5120
        float t = 0.05f * __uint_as_float(tmax[3]);
        float v = wf2[i];
        qwf2[i] = (v > t) ? 1.f : ((v < -t) ? -1.f : 0.f);
    }
}

// ---------------- conv1 fused: conv ONCE + stats + pre-BN maxpool ----------------
__global__ __launch_bounds__(256) void conv1_fused_k(const float* __restrict__ x,
                                                     const float* __restrict__ qw1,
                                                     u16* __restrict__ y1p,
                                                     float* sum1c, float* ssq1c) {
    __shared__ float wl[800];
    __shared__ float red[4][64];
    for (int i = TID; i < 800; i += 256) wl[i] = qw1[i];
    __syncthreads();
    int p = blockIdx.x * 256 + TID;          // < 4096*384 (grid.x = 6144)
    int cg = p & 15, half = (p >> 4) & 1;
    int pr = p >> 5;                         // n*12 + py
    int py = pr % 12, n = pr / 12;
    int l = TID & 63, wv = TID >> 6;
    const float* xb = x + n * 784 + (2 * py) * 28 + half * 12;
    float patch[6][16];
    #pragma unroll
    for (int r = 0; r < 6; r++) {
        const float4* rp = reinterpret_cast<const float4*>(xb + r * 28);
        #pragma unroll
        for (int qq = 0; qq < 4; qq++) {
            float4 v = rp[qq];
            patch[r][qq * 4 + 0] = v.x; patch[r][qq * 4 + 1] = v.y;
            patch[r][qq * 4 + 2] = v.z; patch[r][qq * 4 + 3] = v.w;
        }
    }
    int c0 = cg * 2;
    float st[4];
    float pm[2][6];
    #pragma unroll
    for (int cc = 0; cc < 2; cc++) {
        const float* wr = &wl[(c0 + cc) * 25];
        float a0[12] = {}, a1[12] = {};
        #pragma unroll
        for (int ky = 0; ky < 5; ky++)
            #pragma unroll
            for (int kx = 0; kx < 5; kx++) {
                float w = wr[ky * 5 + kx];
                #pragma unroll
                for (int ox = 0; ox < 12; ox++) {
                    a0[ox] = fmaf(patch[ky][ox + kx], w, a0[ox]);
                    a1[ox] = fmaf(patch[ky + 1][ox + kx], w, a1[ox]);
                }
            }
        float s = 0.f, q = 0.f;
        #pragma unroll
        for (int ox = 0; ox < 12; ox++) {
            s += a0[ox] + a1[ox];
            q = fmaf(a0[ox], a0[ox], q); q = fmaf(a1[ox], a1[ox], q);
        }
        st[cc] = s; st[2 + cc] = q;
        #pragma unroll
        for (int j = 0; j < 6; j++)
            pm[cc][j] = fmaxf(fmaxf(a0[2 * j], a0[2 * j + 1]),
                              fmaxf(a1[2 * j], a1[2 * j + 1]));
    }
    u16* base = y1p + (size_t)n * 4608 + (py * 12 + half * 6) * 32 + c0;
    #pragma unroll
    for (int j = 0; j < 6; j++) {
        unsigned int u = (unsigned int)f2b(pm[0][j]) | ((unsigned int)f2b(pm[1][j]) << 16);
        *reinterpret_cast<unsigned int*>(base + j * 32) = u;
    }
    #pragma unroll
    for (int t = 0; t < 4; t++) {
        st[t] += __shfl_xor(st[t], 16);
        st[t] += __shfl_xor(st[t], 32);
    }
    if (l < 16) {
        #pragma unroll
        for (int t = 0; t < 4; t++) red[wv][l * 4 + t] = st[t];
    }
    __syncthreads();
    if (TID < 64) {
        float v = red[0][TID] + red[1][TID] + red[2][TID] + red[3][TID];
        int t = TID & 3, ch = (TID >> 2) * 2 + (t & 1);
        float* dst = (t < 2 ? sum1c : ssq1c) + (blockIdx.x & 7) * 32 + ch;
        atomicAdd(dst, v);
    }
}

// ---------------- conv2: MFMA implicit conv; BN1+relu in staging ----------------
// Round-10 changes: (a) A-fragments cached per row R: 55 ds_read_b128/sample
// (was 100) serving 100 MFMAs; (b) swizzle slot=(bq+(xx>>1))&3 — conflict-free
// within each 8-lane cycle group (old bq^(xx&3) collided xx vs xx+4).
__global__ __launch_bounds__(256) void conv2_k(const u16* __restrict__ y1p,
                                               const u16* __restrict__ qw2c,
                                               u16* __restrict__ y2c,
                                               const float* sum1c, const float* ssq1c,
                                               const float* g1, const float* be1,
                                               float* sum, float* ssq) {
    __shared__ float4 hsm4[1176];            // 2 x 9408 B
    __shared__ float scs[32], shs[32];
    char* hsraw = (char*)hsm4;
    int n0 = blockIdx.x * 8;                 // grid.x = 512
    int l = TID & 63, wv = TID >> 6;
    int oc0 = wv * 16;
    int lm = l & 15, lr = (l >> 3) & 1, ox = l & 7, bq = l >> 4;
    if (TID < 32) {
        float s = 0.f, q = 0.f;
        #pragma unroll
        for (int r = 0; r < 8; r++) { s += sum1c[r * 32 + TID]; q += ssq1c[r * 32 + TID]; }
        float m = s * (1.f / 2359296.f);
        float v = q * (1.f / 2359296.f) - m * m;
        float sc = g1[TID] / sqrtf(v + 1e-5f);
        scs[TID] = sc; shs[TID] = be1[TID] - m * sc;
    }
    __syncthreads();
    float scR[8], shR[8];
    {
        int b = TID & 3;
        #pragma unroll
        for (int j = 0; j < 8; j++) { scR[j] = scs[b * 8 + j]; shR[j] = shs[b * 8 + j]; }
    }
    short8 bw[25];
    #pragma unroll
    for (int sh = 0; sh < 25; sh++)
        bw[sh] = *reinterpret_cast<const short8*>(qw2c + ((size_t)sh * 64 + oc0 + lm) * 32 + bq * 8);
    int xy[5];
    #pragma unroll
    for (int kx = 0; kx < 5; kx++) {
        int xx = ox + kx;
        xy[kx] = lr * 784 + xx * 64 + (((bq + (xx >> 1)) & 3) * 16);
    }
    float sacc = 0.f, s2acc = 0.f;
    // stage sample 0 (BN+relu on the fly)
    {
        const uint4* src = reinterpret_cast<const uint4*>(y1p + (size_t)n0 * 4608);
        #pragma unroll
        for (int k = 0; k < 3; k++) {
            if (k < 2 || TID < 64) {
                int i = TID + k * 256;
                int pix = i >> 2, b = i & 3;
                int y = pix / 12, xx = pix - y * 12;
                union { uint4 v; u16 u[8]; } in, out;
                in.v = src[i];
                #pragma unroll
                for (int j = 0; j < 8; j++)
                    out.u[j] = f2b(fmaxf(fmaf(b2f(in.u[j]), scR[j], shR[j]), 0.f));
                *reinterpret_cast<uint4*>(hsraw + y * 784 + xx * 64 + (((b + (xx >> 1)) & 3) * 16)) = out.v;
            }
        }
    }
    #pragma unroll 1
    for (int s = 0; s < 8; s++) {
        __syncthreads();
        if (s < 7) {
            const uint4* src = reinterpret_cast<const uint4*>(y1p + (size_t)(n0 + s + 1) * 4608);
            char* dst = hsraw + ((s + 1) & 1) * 9408;
            #pragma unroll
            for (int k = 0; k < 3; k++) {
                if (k < 2 || TID < 64) {
                    int i = TID + k * 256;
                    int pix = i >> 2, b = i & 3;
                    int y = pix / 12, xx = pix - y * 12;
                    union { uint4 v; u16 u[8]; } in, out;
                    in.v = src[i];
                    #pragma unroll
                    for (int j = 0; j < 8; j++)
                        out.u[j] = f2b(fmaxf(fmaf(b2f(in.u[j]), scR[j], shR[j]), 0.f));
                    *reinterpret_cast<uint4*>(dst + y * 784 + xx * 64 + (((b + (xx >> 1)) & 3) * 16)) = out.v;
                }
            }
        }
        const char* hb = hsraw + (s & 1) * 9408;
        f32x4 acc[4] = {{0.f,0.f,0.f,0.f},{0.f,0.f,0.f,0.f},{0.f,0.f,0.f,0.f},{0.f,0.f,0.f,0.f}};
        #pragma unroll
        for (int R = 0; R <= 10; R++) {
            short8 a[5];
            #pragma unroll
            for (int kx = 0; kx < 5; kx++)
                a[kx] = *reinterpret_cast<const short8*>(hb + xy[kx] + R * 784);
            #pragma unroll
            for (int mt = 0; mt < 4; mt++) {
                int ky = R - 2 * mt;
                if (ky < 0 || ky > 4) continue;
                #pragma unroll
                for (int kx = 0; kx < 5; kx++)
                    acc[mt] = __builtin_amdgcn_mfma_f32_16x16x32_bf16(a[kx], bw[ky * 5 + kx], acc[mt], 0, 0, 0);
            }
        }
        int n = n0 + s;
        #pragma unroll
        for (int mt = 0; mt < 4; mt++) {
            float v0 = acc[mt][0], v1 = acc[mt][1], v2 = acc[mt][2], v3 = acc[mt][3];
            sacc += v0 + v1 + v2 + v3;
            s2acc += v0 * v0 + v1 * v1 + v2 * v2 + v3 * v3;
            ushort4 u = make_ushort4(f2b(v0), f2b(v1), f2b(v2), f2b(v3));
            *reinterpret_cast<ushort4*>(y2c + (size_t)n * 4096 + (oc0 + lm) * 64 + mt * 16 + bq * 4) = u;
        }
    }
    sacc  += __shfl_xor(sacc, 16);  sacc  += __shfl_xor(sacc, 32);
    s2acc += __shfl_xor(s2acc, 16); s2acc += __shfl_xor(s2acc, 32);
    if (l < 16) { atomicAdd(&sum[oc0 + l], sacc); atomicAdd(&ssq[oc0 + l], s2acc); }
}

// ---------------- pool2: BN2 (inline finalize) + relu + maxpool ----------------
__global__ __launch_bounds__(256) void pool2_k(const u16* __restrict__ y2c,
                                               const float* sum2, const float* ssq2,
                                               const float* g2, const float* be2,
                                               u16* __restrict__ h2c) {
    int i = blockIdx.x * 256 + TID;          // < 4096*1024 (grid.x = 16384)
    int px = i & 3, py = (i >> 2) & 3, oc = (i >> 4) & 63, n = i >> 10;
    float m = sum2[oc] * (1.f / 262144.f);
    float v = ssq2[oc] * (1.f / 262144.f) - m * m;
    float s = g2[oc] / sqrtf(v + 1e-5f);
    float t = be2[oc] - m * s;
    size_t base = (size_t)n * 4096 + oc * 64 + (2 * py) * 8 + 2 * px;
    float a = b2f(y2c[base])     * s + t;
    float b = b2f(y2c[base + 1]) * s + t;
    float c = b2f(y2c[base + 8]) * s + t;
    float d = b2f(y2c[base + 9]) * s + t;
    float mm = fmaxf(fmaxf(fmaxf(fmaxf(0.f, a), b), c), d);
    h2c[i] = f2b(mm);
}

// ---------------- fc1: MFMA GEMM -> y3T f32 [512][4096]; bn3 stats in epilogue ----------------
__global__ __launch_bounds__(256) void fc1_k(const u16* __restrict__ h2c,
                                             const u16* __restrict__ qwf1c,
                                             float* __restrict__ y3T,
                                             float* sum3, float* ssq3) {
    __shared__ float4 Asm[576], Bsm[576];
    u16* AsU = (u16*)Asm; u16* BsU = (u16*)Bsm;
    int m0 = blockIdx.x * 64, j0 = blockIdx.y * 64;
    int l = TID & 63, wv = TID >> 6;
    int lm = l & 15, q = l >> 4;
    int r0 = TID >> 3, c0 = TID & 7;
    f32x4 acc[4] = {{0.f,0.f,0.f,0.f},{0.f,0.f,0.f,0.f},{0.f,0.f,0.f,0.f},{0.f,0.f,0.f,0.f}};
    #pragma unroll 1
    for (int kc = 0; kc < 16; kc++) {
        int kk = kc * 64;
        if (kc) __syncthreads();
        #pragma unroll
        for (int i = 0; i < 2; i++) {
            int r = i * 32 + r0;
            *reinterpret_cast<float4*>(AsU + r * 72 + c0 * 8) =
                *reinterpret_cast<const float4*>(h2c + (size_t)(m0 + r) * 1024 + kk + c0 * 8);
            *reinterpret_cast<float4*>(BsU + r * 72 + c0 * 8) =
                *reinterpret_cast<const float4*>(qwf1c + (size_t)(j0 + r) * 1024 + kk + c0 * 8);
        }
        __syncthreads();
        #pragma unroll
        for (int half = 0; half < 2; half++) {
            short8 b = *reinterpret_cast<const short8*>(BsU + (wv * 16 + lm) * 72 + half * 32 + q * 8);
            #pragma unroll
            for (int mt = 0; mt < 4; mt++) {
                short8 a = *reinterpret_cast<const short8*>(AsU + (mt * 16 + lm) * 72 + half * 32 + q * 8);
                acc[mt] = __builtin_amdgcn_mfma_f32_16x16x32_bf16(a, b, acc[mt], 0, 0, 0);
            }
        }
    }
    float s = 0.f, s2 = 0.f;
    #pragma unroll
    for (int mt = 0; mt < 4; mt++) {
        *reinterpret_cast<f32x4*>(y3T + (size_t)(j0 + wv * 16 + lm) * 4096 + m0 + mt * 16 + q * 4) = acc[mt];
        #pragma unroll
        for (int i = 0; i < 4; i++) { float v = acc[mt][i]; s += v; s2 = fmaf(v, v, s2); }
    }
    s  += __shfl_xor(s, 16);  s  += __shfl_xor(s, 32);
    s2 += __shfl_xor(s2, 16); s2 += __shfl_xor(s2, 32);
    if (l < 16) {
        atomicAdd(&sum3[j0 + wv * 16 + l], s);
        atomicAdd(&ssq3[j0 + wv * 16 + l], s2);
    }
}

// ---------------- fc2: BN3 inline + relu + GEMV; grid 256 = 16 n x 16 kslices ----------------
__global__ __launch_bounds__(256) void fc2_k(const float* __restrict__ y3T,
                                             const float* sum3, const float* ssq3,
                                             const float* g3, const float* be3,
                                             const float* __restrict__ qwf2,
                                             const float* bf2, float* __restrict__ out) {
    __shared__ float wlds[5120];
    __shared__ float part[15][160];
    __shared__ float sc3s[512], sh3s[512];
    for (int i = TID; i < 5120; i += 256) wlds[i] = qwf2[i];
    for (int k = TID; k < 512; k += 256) {
        float m = sum3[k] * (1.f / 4096.f);
        float v = ssq3[k] * (1.f / 4096.f) - m * m;
        float s = g3[k] / sqrtf(v + 1e-5f);
        sc3s[k] = s; sh3s[k] = be3[k] - m * s;
    }
    __syncthreads();
    int nl = TID & 15, ks = TID >> 4;
    int n = blockIdx.x * 16 + nl;            // grid.x = 256
    float acc[10] = {};
    for (int k = ks * 32; k < ks * 32 + 32; k++) {
        float v = fmaxf(y3T[(size_t)k * 4096 + n] * sc3s[k] + sh3s[k], 0.f);
        #pragma unroll
        for (int o = 0; o < 10; o++) acc[o] = fmaf(v, wlds[o * 512 + k], acc[o]);
    }
    if (ks > 0) {
        #pragma unroll
        for (int o = 0; o < 10; o++) part[ks - 1][o * 16 + nl] = acc[o];
    }
    __syncthreads();
    if (ks == 0) {
        #pragma unroll
        for (int o = 0; o < 10; o++) {
            float r = acc[o] + bf2[o];
            #pragma unroll
            for (int j = 0; j < 15; j++) r += part[j][o * 16 + nl];
            out[n * 10 + o] = r;
        }
    }
}

extern "C" void kernel_launch(void* const* d_in, const int* in_sizes, int n_in,
                              void* d_out, int out_size, void* d_ws, size_t ws_size,
                              hipStream_t stream) {
    char* wsb = (char*)d_ws;
    const float* x   = (const float*)d_in[0];
    const float* w1  = (const float*)d_in[1];
    // b1/b2/bf1 cancel under training-mode BN
    const float* g1  = (const float*)d_in[3];
    const float* be1 = (const float*)d_in[4];
    const float* w2  = (const float*)d_in[5];
    const float* g2  = (const float*)d_in[7];
    const float* be2 = (const float*)d_in[8];
    const float* wf1 = (const float*)d_in[9];
    const float* g3  = (const float*)d_in[11];
    const float* be3 = (const float*)d_in[12];
    const float* wf2 = (const float*)d_in[13];
    const float* bf2 = (const float*)d_in[14];
    float* out = (float*)d_out;

    unsigned int* tmax = (unsigned int*)(wsb + OFF_TMAX);
    float* qw1   = (float*)(wsb + OFF_QW1);
    float* qwf2  = (float*)(wsb + OFF_QWF2);
    u16*   qw2c  = (u16*)(wsb + OFF_QW2C);
    u16*   qwf1c = (u16*)(wsb + OFF_QWF1C);
    u16*   y1p   = (u16*)(wsb + OFF_Y1P);
    u16*   y2c   = (u16*)(wsb + OFF_Y2C);
    u16*   h2c   = (u16*)(wsb + OFF_H2C);
    float* y3    = (float*)(wsb + OFF_Y3);

    float* sum1c = (float*)(wsb + OFF_SUM1C); float* ssq1c = (float*)(wsb + OFF_SSQ1C);
    float* sum2  = (float*)(wsb + OFF_SUM2);  float* ssq2  = (float*)(wsb + OFF_SSQ2);
    float* sum3  = (float*)(wsb + OFF_SUM3);  float* ssq3  = (float*)(wsb + OFF_SSQ3);

    hipMemsetAsync(wsb + STATS_BEG, 0, STATS_END - STATS_BEG, stream);

    absmax_k<<<266, 256, 0, stream>>>(w1, w2, wf1, wf2, tmax);
    quant_all_k<<<2272, 256, 0, stream>>>(w1, w2, wf1, wf2, qw1, qw2c, qwf1c, qwf2, tmax);

    conv1_fused_k<<<6144, 256, 0, stream>>>(x, qw1, y1p, sum1c, ssq1c);
    conv2_k<<<512, 256, 0, stream>>>(y1p, qw2c, y2c, sum1c, ssq1c, g1, be1, sum2, ssq2);
    pool2_k<<<16384, 256, 0, stream>>>(y2c, sum2, ssq2, g2, be2, h2c);
    fc1_k<<<dim3(64, 8), 256, 0, stream>>>(h2c, qwf1c, y3, sum3, ssq3);
    fc2_k<<<256, 256, 0, stream>>>(y3, sum3, ssq3, g3, be3, qwf2, bf2, out);
}